// Round 1
// baseline (1688.402 us; speedup 1.0000x reference)
//
#include <hip/hip_runtime.h>
#include <hip/hip_bf16.h>
#include <math.h>

#define L_ 2
#define P_ 3
#define R_ 512
#define A_ 196
#define V_ 9487
#define B_ 256
#define BR (B_*R_)   /* 131072 */
#define G4 (4*R_)    /* 2048 */

// ---------------------------------------------------------------------------
// Fused score kernel: score[m] = sum_k tanh( att[m,:]·a2aw[k,:] + a2ab[k]
//                                            + h[b]·h2aw[a] + h2ab[a] ) * d2dw[k]  + d2db
// m = b*A + a ; k in [0,196) padded to 256.
// GEMM M-tile 64 (flat att rows), N = 256 (padded), K = 512, KT = 32.
// NOTE: a2ab[k] — wait, reference adds a2a_b to v. Handled via wpad trick below? No:
// v = att@a2aw^T + a2ab  (bias over k). We add a2ab into the accumulator via epilogue.
// ---------------------------------------------------------------------------
__global__ __launch_bounds__(256) void k_score(
    const float* __restrict__ att, const float* __restrict__ h,
    const float* __restrict__ a2aw, const float* __restrict__ a2ab,
    const float* __restrict__ h2aw, const float* __restrict__ h2ab,
    const float* __restrict__ d2dw, const float* __restrict__ d2db,
    float* __restrict__ score)
{
  __shared__ __align__(16) float As[32][68];
  __shared__ __align__(16) float Bs[32][256];
  __shared__ float wpad[256];   // d2dw padded with zeros
  __shared__ float bpad[256];   // a2ab padded with zeros
  __shared__ float hhs[64];
  __shared__ float hred[64][5];
  __shared__ float sred[16][68];

  const int t  = threadIdx.x;
  const int m0 = blockIdx.x * 64;

  wpad[t] = (t < A_) ? d2dw[t] : 0.f;
  bpad[t] = (t < A_) ? a2ab[t] : 0.f;

  float acc[4][4][4];
#pragma unroll
  for (int r = 0; r < 4; ++r)
#pragma unroll
    for (int q = 0; q < 4; ++q)
#pragma unroll
      for (int j = 0; j < 4; ++j) acc[r][q][j] = 0.f;

  const int r0 = (t >> 4) << 2;   // 0..60
  const int cb = (t & 15) << 2;   // 0..60 ; cols cb + 64*q + j

  const int s_row = t >> 2;          // 0..63
  const int s_kb  = (t & 3) << 3;    // 0,8,16,24
  const float* agp = att + (size_t)(m0 + s_row) * R_ + s_kb;
  const int w_col = t;
  const bool wvalid = (w_col < A_);
  const float* wgp = a2aw + (size_t)(wvalid ? w_col : 0) * R_;

  if (!wvalid) {
#pragma unroll
    for (int c = 0; c < 32; ++c) Bs[c][w_col] = 0.f;   // stays zero for all tiles
  }

  for (int k0 = 0; k0 < R_; k0 += 32) {
    __syncthreads();
    {
      float4 v0 = *(const float4*)(agp + k0);
      float4 v1 = *(const float4*)(agp + k0 + 4);
      As[s_kb+0][s_row] = v0.x; As[s_kb+1][s_row] = v0.y;
      As[s_kb+2][s_row] = v0.z; As[s_kb+3][s_row] = v0.w;
      As[s_kb+4][s_row] = v1.x; As[s_kb+5][s_row] = v1.y;
      As[s_kb+6][s_row] = v1.z; As[s_kb+7][s_row] = v1.w;
    }
    if (wvalid) {
#pragma unroll
      for (int c = 0; c < 8; ++c) {
        float4 v = *(const float4*)(wgp + k0 + 4*c);
        Bs[4*c+0][w_col] = v.x; Bs[4*c+1][w_col] = v.y;
        Bs[4*c+2][w_col] = v.z; Bs[4*c+3][w_col] = v.w;
      }
    }
    __syncthreads();
#pragma unroll
    for (int kk = 0; kk < 32; ++kk) {
      const float4 av = *(const float4*)&As[kk][r0];
      const float4 b0 = *(const float4*)&Bs[kk][cb];
      const float4 b1 = *(const float4*)&Bs[kk][cb+64];
      const float4 b2 = *(const float4*)&Bs[kk][cb+128];
      const float4 b3 = *(const float4*)&Bs[kk][cb+192];
      const float ar4[4] = {av.x, av.y, av.z, av.w};
      const float bb[4][4] = {{b0.x,b0.y,b0.z,b0.w},{b1.x,b1.y,b1.z,b1.w},
                              {b2.x,b2.y,b2.z,b2.w},{b3.x,b3.y,b3.z,b3.w}};
#pragma unroll
      for (int r = 0; r < 4; ++r)
#pragma unroll
        for (int q = 0; q < 4; ++q)
#pragma unroll
          for (int j = 0; j < 4; ++j)
            acc[r][q][j] = fmaf(ar4[r], bb[q][j], acc[r][q][j]);
    }
  }
  __syncthreads();
  // hh[row] = h[b_row]·h2aw[a_row] + h2ab[a_row]
  {
    const int row = t >> 2, seg = t & 3;
    const int m = m0 + row;
    const int b_r = m / A_;
    const int a_r = m - b_r * A_;
    const float* hp = h    + (size_t)b_r * R_ + seg * 128;
    const float* wp = h2aw + (size_t)a_r * R_ + seg * 128;
    float p = 0.f;
#pragma unroll
    for (int k = 0; k < 128; k += 4) {
      float4 a4 = *(const float4*)(hp + k);
      float4 b4 = *(const float4*)(wp + k);
      p = fmaf(a4.x, b4.x, p); p = fmaf(a4.y, b4.y, p);
      p = fmaf(a4.z, b4.z, p); p = fmaf(a4.w, b4.w, p);
    }
    hred[row][seg] = p;
  }
  __syncthreads();
  if (t < 64) {
    const int m = m0 + t;
    const int b_r = m / A_;
    const int a_r = m - b_r * A_;
    hhs[t] = hred[t][0] + hred[t][1] + hred[t][2] + hred[t][3] + h2ab[a_r];
  }
  __syncthreads();
#pragma unroll
  for (int r = 0; r < 4; ++r) {
    const float hv = hhs[r0 + r];
    float s = 0.f;
#pragma unroll
    for (int q = 0; q < 4; ++q)
#pragma unroll
      for (int j = 0; j < 4; ++j) {
        const int col = cb + 64*q + j;
        s += tanhf(acc[r][q][j] + bpad[col] + hv) * wpad[col];
      }
    sred[t & 15][r0 + r] = s;
  }
  __syncthreads();
  if (t < 64) {
    float s = 0.f;
#pragma unroll
    for (int g = 0; g < 16; ++g) s += sred[g][t];
    score[m0 + t] = s + d2db[0];
  }
}

// softmax over a (196) per batch row, in place
__global__ __launch_bounds__(256) void k_softmax_att(float* __restrict__ sc)
{
  __shared__ float red[256];
  const int b = blockIdx.x, t = threadIdx.x;
  float v = (t < A_) ? sc[b*A_ + t] : -INFINITY;
  red[t] = v; __syncthreads();
  for (int s = 128; s > 0; s >>= 1) { if (t < s) red[t] = fmaxf(red[t], red[t+s]); __syncthreads(); }
  const float mx = red[0]; __syncthreads();
  const float e = (t < A_) ? expf(v - mx) : 0.f;
  red[t] = e; __syncthreads();
  for (int s = 128; s > 0; s >>= 1) { if (t < s) red[t] += red[t+s]; __syncthreads(); }
  if (t < A_) sc[b*A_ + t] = e / red[0];
}

// att_res[b,r] = sum_a att[b,a,r] * w[b,a]
__global__ __launch_bounds__(256) void k_attres(
    const float* __restrict__ att, const float* __restrict__ w, float* __restrict__ out)
{
  __shared__ float wl[A_];
  const int b = blockIdx.x, t = threadIdx.x;
  if (t < A_) wl[t] = w[b*A_ + t];
  __syncthreads();
  const int r = blockIdx.y * 256 + t;
  const float* ap = att + (size_t)b * A_ * R_ + r;
  float acc = 0.f;
#pragma unroll 4
  for (int a = 0; a < A_; ++a) acc = fmaf(ap[(size_t)a * R_], wl[a], acc);
  out[b * R_ + r] = acc;
}

// sums[p,b,g] = xt·i2h_w + ph·h2h_w + ar·a2h_w   (no biases; added in k_lstm_elem)
// GEMM M=256(b) tile 64, N=6144(p*2048+g) tile 128, K=1536 (3 segments of 512)
__global__ __launch_bounds__(256) void k_lstm_gemm(
    const float* __restrict__ xt, const float* __restrict__ ph, const float* __restrict__ ar,
    const float* __restrict__ i2hw, const float* __restrict__ h2hw, const float* __restrict__ a2hw,
    int layer, float* __restrict__ sums)
{
  __shared__ __align__(16) float As[32][68];
  __shared__ __align__(16) float Bs[32][128];
  const int t  = threadIdx.x;
  const int m0 = blockIdx.x * 64;
  const int n0 = blockIdx.y * 128;
  float acc[4][2][4];
#pragma unroll
  for (int r = 0; r < 4; ++r)
#pragma unroll
    for (int q = 0; q < 2; ++q)
#pragma unroll
      for (int j = 0; j < 4; ++j) acc[r][q][j] = 0.f;

  const int r0 = (t >> 4) << 2;
  const int cb = (t & 15) << 2;
  const size_t wbase = (size_t)layer * 6144 * 512;

  for (int k0 = 0; k0 < 1536; k0 += 32) {
    const int seg  = k0 >> 9;
    const int kloc = k0 & 511;
    __syncthreads();
    if (t < 128) {
      const float* wsrc = (seg == 0) ? i2hw : (seg == 1) ? h2hw : a2hw;
      const float* gp = wsrc + wbase + (size_t)(n0 + t) * 512 + kloc;
#pragma unroll
      for (int c = 0; c < 8; ++c) {
        float4 v = *(const float4*)(gp + 4*c);
        Bs[4*c+0][t] = v.x; Bs[4*c+1][t] = v.y; Bs[4*c+2][t] = v.z; Bs[4*c+3][t] = v.w;
      }
    } else {
      const int tt  = t - 128;
      const int row = tt >> 1;
      const int kb  = (tt & 1) << 4;
      const float* asrc = (seg == 0) ? xt : (seg == 1) ? ph : ar;
      const float* gp = asrc + (size_t)(m0 + row) * 512 + kloc + kb;
#pragma unroll
      for (int c = 0; c < 4; ++c) {
        float4 v = *(const float4*)(gp + 4*c);
        As[kb+4*c+0][row] = v.x; As[kb+4*c+1][row] = v.y;
        As[kb+4*c+2][row] = v.z; As[kb+4*c+3][row] = v.w;
      }
    }
    __syncthreads();
#pragma unroll
    for (int kk = 0; kk < 32; ++kk) {
      const float4 av = *(const float4*)&As[kk][r0];
      const float4 b0 = *(const float4*)&Bs[kk][cb];
      const float4 b1 = *(const float4*)&Bs[kk][cb+64];
      const float ar4[4] = {av.x, av.y, av.z, av.w};
      const float bb[2][4] = {{b0.x,b0.y,b0.z,b0.w},{b1.x,b1.y,b1.z,b1.w}};
#pragma unroll
      for (int r = 0; r < 4; ++r)
#pragma unroll
        for (int q = 0; q < 2; ++q)
#pragma unroll
          for (int j = 0; j < 4; ++j)
            acc[r][q][j] = fmaf(ar4[r], bb[q][j], acc[r][q][j]);
    }
  }
#pragma unroll
  for (int r = 0; r < 4; ++r) {
    const int b = m0 + r0 + r;
#pragma unroll
    for (int q = 0; q < 2; ++q) {
      const int n = n0 + cb + 64*q;
      const int p = n >> 11, g = n & 2047;
      float4 v = make_float4(acc[r][q][0], acc[r][q][1], acc[r][q][2], acc[r][q][3]);
      *(float4*)&sums[((size_t)p * B_ + b) * (size_t)G4 + g] = v;
    }
  }
}

__global__ __launch_bounds__(256) void k_lstm_elem(
    const float* __restrict__ sums,
    const float* __restrict__ i2hb, const float* __restrict__ h2hb, const float* __restrict__ a2hb,
    const float* __restrict__ prev_c, int layer,
    float* __restrict__ out_c, float* __restrict__ next_h)
{
  const int idx = blockIdx.x * 256 + threadIdx.x;  // 0..131071
  const int b = idx >> 9, r = idx & 511;
  const size_t boff = (size_t)layer * P_ * G4;
  const float pc = prev_c[idx];
  float aC = 0.f, aH = 0.f;
#pragma unroll
  for (int p = 0; p < P_; ++p) {
    const float* sp = sums + ((size_t)p * B_ + b) * (size_t)G4;
    const float* b1 = i2hb + boff + p * G4;
    const float* b2 = h2hb + boff + p * G4;
    const float* b3 = a2hb + boff + p * G4;
    const float gi = sp[r]      + b1[r]      + b2[r]      + b3[r];
    const float gf = sp[r+512]  + b1[r+512]  + b2[r+512]  + b3[r+512];
    const float go = sp[r+1024] + b1[r+1024] + b2[r+1024] + b3[r+1024];
    const float gt = sp[r+1536] + b1[r+1536] + b2[r+1536] + b3[r+1536];
    const float ig = 1.f / (1.f + expf(-gi));
    const float fg = 1.f / (1.f + expf(-gf));
    const float og = 1.f / (1.f + expf(-go));
    const float it = tanhf(gt);
    const float nc = fg * pc + ig * it;
    const float nh = og * tanhf(nc);
    aC += nc; aH += nh;
  }
  out_c[idx]  = aC * (1.f/3.f);
  next_h[idx] = aH * (1.f/3.f);
}

__global__ __launch_bounds__(256) void k_toph(
    const float* __restrict__ attres, const float* __restrict__ nh, const float* __restrict__ x,
    float* __restrict__ out_slot, float* __restrict__ toph, float* __restrict__ xt_next, int make_xt)
{
  const int idx = blockIdx.x * 256 + threadIdx.x;
  const float v = attres[idx] + nh[idx];
  out_slot[idx] = v;
  toph[idx] = v;
  if (make_xt) xt_next[idx] = x[idx] + v;
}

// logits = toph @ proj_w^T + proj_b ; M=256 tile 64, N=9487 tile 128, K=512
__global__ __launch_bounds__(256) void k_proj(
    const float* __restrict__ th, const float* __restrict__ pw, const float* __restrict__ pb,
    float* __restrict__ logits)
{
  __shared__ __align__(16) float As[32][68];
  __shared__ __align__(16) float Bs[32][128];
  const int t  = threadIdx.x;
  const int m0 = blockIdx.x * 64;
  const int n0 = blockIdx.y * 128;
  float acc[4][2][4];
#pragma unroll
  for (int r = 0; r < 4; ++r)
#pragma unroll
    for (int q = 0; q < 2; ++q)
#pragma unroll
      for (int j = 0; j < 4; ++j) acc[r][q][j] = 0.f;

  const int r0 = (t >> 4) << 2;
  const int cb = (t & 15) << 2;
  const bool colvalid = (t < 128) && (n0 + t < V_);
  if (t < 128 && !colvalid) {
#pragma unroll
    for (int c = 0; c < 32; ++c) Bs[c][t] = 0.f;
  }

  for (int k0 = 0; k0 < 512; k0 += 32) {
    __syncthreads();
    if (t < 128) {
      if (colvalid) {
        const float* gp = pw + (size_t)(n0 + t) * 512 + k0;
#pragma unroll
        for (int c = 0; c < 8; ++c) {
          float4 v = *(const float4*)(gp + 4*c);
          Bs[4*c+0][t] = v.x; Bs[4*c+1][t] = v.y; Bs[4*c+2][t] = v.z; Bs[4*c+3][t] = v.w;
        }
      }
    } else {
      const int tt  = t - 128;
      const int row = tt >> 1;
      const int kb  = (tt & 1) << 4;
      const float* gp = th + (size_t)(m0 + row) * 512 + k0 + kb;
#pragma unroll
      for (int c = 0; c < 4; ++c) {
        float4 v = *(const float4*)(gp + 4*c);
        As[kb+4*c+0][row] = v.x; As[kb+4*c+1][row] = v.y;
        As[kb+4*c+2][row] = v.z; As[kb+4*c+3][row] = v.w;
      }
    }
    __syncthreads();
#pragma unroll
    for (int kk = 0; kk < 32; ++kk) {
      const float4 av = *(const float4*)&As[kk][r0];
      const float4 b0 = *(const float4*)&Bs[kk][cb];
      const float4 b1 = *(const float4*)&Bs[kk][cb+64];
      const float ar4[4] = {av.x, av.y, av.z, av.w};
      const float bb[2][4] = {{b0.x,b0.y,b0.z,b0.w},{b1.x,b1.y,b1.z,b1.w}};
#pragma unroll
      for (int r = 0; r < 4; ++r)
#pragma unroll
        for (int q = 0; q < 2; ++q)
#pragma unroll
          for (int j = 0; j < 4; ++j)
            acc[r][q][j] = fmaf(ar4[r], bb[q][j], acc[r][q][j]);
    }
  }
#pragma unroll
  for (int r = 0; r < 4; ++r) {
    const int b = m0 + r0 + r;
#pragma unroll
    for (int q = 0; q < 2; ++q) {
      const int n = n0 + cb + 64*q;
#pragma unroll
      for (int j = 0; j < 4; ++j) {
        if (n + j < V_) logits[(size_t)b * V_ + n + j] = acc[r][q][j] + pb[n + j];
      }
    }
  }
}

__global__ __launch_bounds__(256) void k_logsoftmax(
    const float* __restrict__ logits, float* __restrict__ out)
{
  __shared__ float red[256];
  const int b = blockIdx.x, t = threadIdx.x;
  const float* lp = logits + (size_t)b * V_;
  float mx = -INFINITY;
  for (int n = t; n < V_; n += 256) mx = fmaxf(mx, lp[n]);
  red[t] = mx; __syncthreads();
  for (int s = 128; s > 0; s >>= 1) { if (t < s) red[t] = fmaxf(red[t], red[t+s]); __syncthreads(); }
  mx = red[0]; __syncthreads();
  float sm = 0.f;
  for (int n = t; n < V_; n += 256) sm += expf(lp[n] - mx);
  red[t] = sm; __syncthreads();
  for (int s = 128; s > 0; s >>= 1) { if (t < s) red[t] += red[t+s]; __syncthreads(); }
  const float lse = mx + logf(red[0]);
  float* op = out + (size_t)b * V_;
  for (int n = t; n < V_; n += 256) op[n] = lp[n] - lse;
}

extern "C" void kernel_launch(void* const* d_in, const int* in_sizes, int n_in,
                              void* d_out, int out_size, void* d_ws, size_t ws_size,
                              hipStream_t stream)
{
  const float* x      = (const float*)d_in[0];
  const float* att    = (const float*)d_in[1];
  const float* inputs = (const float*)d_in[2];
  const float* i2hw   = (const float*)d_in[3];
  const float* i2hb   = (const float*)d_in[4];
  const float* h2hw   = (const float*)d_in[5];
  const float* h2hb   = (const float*)d_in[6];
  const float* a2hw   = (const float*)d_in[7];
  const float* a2hb   = (const float*)d_in[8];
  const float* a2aw   = (const float*)d_in[9];
  const float* a2ab   = (const float*)d_in[10];
  const float* h2aw   = (const float*)d_in[11];
  const float* h2ab   = (const float*)d_in[12];
  const float* d2dw   = (const float*)d_in[13];
  const float* d2db   = (const float*)d_in[14];
  const float* pw     = (const float*)d_in[15];
  const float* pb     = (const float*)d_in[16];
  float* out = (float*)d_out;
  float* ws  = (float*)d_ws;

  float* w_score  = ws + 0;        // 50176
  float* w_attres = ws + 65536;    // 131072
  float* w_xt     = ws + 196608;   // 131072
  float* w_nexth  = ws + 327680;   // 131072
  float* w_toph   = ws + 458752;   // 131072
  float* w_sums   = ws + 589824;   // 1572864
  float* w_logits = ws + 2162688;  // 2428672  (total 4,591,360 floats = 18.4 MB)

  const float* cur_x = x;
  for (int i = 0; i < L_; ++i) {
    const float* prev_c = inputs + (size_t)(2*i)   * BR;
    const float* prev_h = inputs + (size_t)(2*i+1) * BR;

    // --- att_res0 = soft_att(att, prev_h, weights[i,0]) ---
    {
      const int idx = i*2 + 0;
      k_score<<<784, 256, 0, stream>>>(att, prev_h,
          a2aw + (size_t)idx*A_*R_, a2ab + (size_t)idx*A_,
          h2aw + (size_t)idx*A_*R_, h2ab + (size_t)idx*A_,
          d2dw + (size_t)idx*A_, d2db + idx, w_score);
      k_softmax_att<<<B_, 256, 0, stream>>>(w_score);
      k_attres<<<dim3(B_, 2), 256, 0, stream>>>(att, w_score, w_attres);
    }

    // --- LSTM ---
    k_lstm_gemm<<<dim3(4, 48), 256, 0, stream>>>(cur_x, prev_h, w_attres,
                                                 i2hw, h2hw, a2hw, i, w_sums);
    k_lstm_elem<<<512, 256, 0, stream>>>(w_sums, i2hb, h2hb, a2hb, prev_c, i,
                                         out + (size_t)(2*i) * BR, w_nexth);

    // --- att_res1 = soft_att(att, next_h, weights[i,1]) ---
    {
      const int idx = i*2 + 1;
      k_score<<<784, 256, 0, stream>>>(att, w_nexth,
          a2aw + (size_t)idx*A_*R_, a2ab + (size_t)idx*A_,
          h2aw + (size_t)idx*A_*R_, h2ab + (size_t)idx*A_,
          d2dw + (size_t)idx*A_, d2db + idx, w_score);
      k_softmax_att<<<B_, 256, 0, stream>>>(w_score);
      k_attres<<<dim3(B_, 2), 256, 0, stream>>>(att, w_score, w_attres);
    }

    // --- top_h = att_res1 + next_h ; xt for next layer = x + top_h ---
    k_toph<<<512, 256, 0, stream>>>(w_attres, w_nexth, x,
                                    out + (size_t)(2*i+1) * BR, w_toph, w_xt,
                                    (i == 0) ? 1 : 0);
    cur_x = w_xt;
  }

  k_proj<<<dim3(4, 75), 256, 0, stream>>>(w_toph, pw, pb, w_logits);
  k_logsoftmax<<<B_, 256, 0, stream>>>(w_logits, out + (size_t)4 * BR);
}

// Round 3
// 752.049 us; speedup vs baseline: 2.2451x; 2.2451x over previous
//
#include <hip/hip_runtime.h>
#include <hip/hip_bf16.h>
#include <math.h>

#define L_ 2
#define P_ 3
#define R_ 512
#define A_ 196
#define V_ 9487
#define B_ 256
#define BR (B_*R_)   /* 131072 */
#define G4 (4*R_)    /* 2048 */

typedef short bf16x8 __attribute__((ext_vector_type(8)));
typedef float f32x4  __attribute__((ext_vector_type(4)));

static __device__ __forceinline__ unsigned short f2b(float f){
  unsigned int u = __builtin_bit_cast(unsigned int, f);
  u += 0x7fffu + ((u >> 16) & 1u);
  return (unsigned short)(u >> 16);
}
static __device__ __forceinline__ bf16x8 cvt8(float4 a, float4 b){
  bf16x8 r;
  r[0]=(short)f2b(a.x); r[1]=(short)f2b(a.y); r[2]=(short)f2b(a.z); r[3]=(short)f2b(a.w);
  r[4]=(short)f2b(b.x); r[5]=(short)f2b(b.y); r[6]=(short)f2b(b.z); r[7]=(short)f2b(b.w);
  return r;
}

// generic fp32 -> bf16 elementwise convert (n multiple of 8)
__global__ __launch_bounds__(256) void k_cvt(const float* __restrict__ src,
                                             short* __restrict__ dst, int n)
{
  const int c = blockIdx.x * 256 + threadIdx.x;
  const int base = c * 8;
  if (base >= n) return;
  float4 a = *(const float4*)(src + base);
  float4 b = *(const float4*)(src + base + 4);
  *(bf16x8*)(dst + base) = cvt8(a, b);
}

// hh[m] = h[b]·h2aw[a] + h2ab[a],  m = b*196 + a ; 64 rows per block
__global__ __launch_bounds__(256) void k_hh(
    const float* __restrict__ h, const float* __restrict__ hw,
    const float* __restrict__ hb, float* __restrict__ out)
{
  __shared__ float hred[64][5];
  const int t = threadIdx.x;
  const int row = blockIdx.x * 64 + (t >> 2);
  const int seg = t & 3;
  const int b = row / A_;
  const int a = row - b * A_;
  const float* hp = h  + (size_t)b * R_ + seg * 128;
  const float* wp = hw + (size_t)a * R_ + seg * 128;
  float p = 0.f;
#pragma unroll
  for (int k = 0; k < 128; k += 4) {
    float4 a4 = *(const float4*)(hp + k);
    float4 b4 = *(const float4*)(wp + k);
    p = fmaf(a4.x, b4.x, p); p = fmaf(a4.y, b4.y, p);
    p = fmaf(a4.z, b4.z, p); p = fmaf(a4.w, b4.w, p);
  }
  hred[t >> 2][seg] = p;
  __syncthreads();
  if (t < 64) {
    const int m = blockIdx.x * 64 + t;
    const int b2 = m / A_;
    const int a2 = m - b2 * A_;
    out[m] = hred[t][0] + hred[t][1] + hred[t][2] + hred[t][3] + hb[a2];
  }
}

// ---------------------------------------------------------------------------
// Score via MFMA: C[m, n] = att[m,:] (fp32, cvt on the fly) @ W_bf[n,:]^T
// then score[m] = sum_n tanh(C + a2ab[n] + hh[m]) * d2dw[n] + d2db.
// M_tile=64, N=224 (196 zero-padded), K=512, K-step 32.
// 4 waves 2(M)x2(N): wave M_rep=2, N_rep=7.
// LDS k-major [kb][row][8 bf16] -> conflict-free ds_read_b128 frags.
// ---------------------------------------------------------------------------
__global__ __launch_bounds__(256) void k_score_mfma(
    const float* __restrict__ att, const short* __restrict__ wbf,
    const float* __restrict__ a2ab, const float* __restrict__ d2dw,
    const float* __restrict__ d2db, const float* __restrict__ hh,
    float* __restrict__ score)
{
  __shared__ __align__(16) short As[4 * 64 * 8];    // 4 KiB
  __shared__ __align__(16) short Bs[4 * 224 * 8];   // 14 KiB
  __shared__ float wpad[224], bpad[224], hhs[64], sred[2][64];

  const int t   = threadIdx.x;
  const int m0  = blockIdx.x * 64;
  const int wid = t >> 6, l = t & 63;
  const int wr  = wid >> 1, wc = wid & 1;
  const int q   = l >> 4, lc = l & 15;

  if (t < 224) { wpad[t] = (t < A_) ? d2dw[t] : 0.f; bpad[t] = (t < A_) ? a2ab[t] : 0.f; }
  if (t < 64)  hhs[t] = hh[m0 + t];

  f32x4 acc[2][7];
#pragma unroll
  for (int i = 0; i < 2; ++i)
#pragma unroll
    for (int j = 0; j < 7; ++j) acc[i][j] = (f32x4){0.f, 0.f, 0.f, 0.f};

  const int s_row = t >> 2, s_kb = t & 3;
  const float* asrc = att + (size_t)(m0 + s_row) * R_ + s_kb * 8;
  const int n3 = 192 + s_row;   // j=3 B row (t<128 only)

  float4 ra0, ra1;
  bf16x8 rb0, rb1, rb2, rb3;

#define SC_LOAD(ks) {                                                   \
    const int k0 = (ks) * 32;                                           \
    ra0 = *(const float4*)(asrc + k0);                                  \
    ra1 = *(const float4*)(asrc + k0 + 4);                              \
    const int koff = k0 + s_kb * 8;                                     \
    rb0 = *(const bf16x8*)(wbf + (size_t)(s_row      ) * R_ + koff);    \
    rb1 = *(const bf16x8*)(wbf + (size_t)(s_row +  64) * R_ + koff);    \
    rb2 = *(const bf16x8*)(wbf + (size_t)(s_row + 128) * R_ + koff);    \
    if (t < 128) {                                                      \
      if (n3 < A_) rb3 = *(const bf16x8*)(wbf + (size_t)n3 * R_ + koff);\
      else         rb3 = (bf16x8){0,0,0,0,0,0,0,0};                     \
    }                                                                   \
  }
#define SC_STORE() {                                                    \
    *(bf16x8*)&As[s_kb * 512  + s_row * 8] = cvt8(ra0, ra1);            \
    *(bf16x8*)&Bs[s_kb * 1792 + (s_row      ) * 8] = rb0;               \
    *(bf16x8*)&Bs[s_kb * 1792 + (s_row +  64) * 8] = rb1;               \
    *(bf16x8*)&Bs[s_kb * 1792 + (s_row + 128) * 8] = rb2;               \
    if (t < 128) *(bf16x8*)&Bs[s_kb * 1792 + n3 * 8] = rb3;             \
  }

  SC_LOAD(0);
  for (int ks = 0; ks < 16; ++ks) {
    __syncthreads();
    SC_STORE();
    __syncthreads();
    if (ks < 15) SC_LOAD(ks + 1);
    bf16x8 af[2], bfr[7];
#pragma unroll
    for (int mf = 0; mf < 2; ++mf) {
      const int row = wr * 32 + mf * 16 + lc;
      af[mf] = *(const bf16x8*)&As[q * 512 + row * 8];
    }
#pragma unroll
    for (int nf = 0; nf < 7; ++nf) {
      const int n = wc * 112 + nf * 16 + lc;
      bfr[nf] = *(const bf16x8*)&Bs[q * 1792 + n * 8];
    }
#pragma unroll
    for (int mf = 0; mf < 2; ++mf)
#pragma unroll
      for (int nf = 0; nf < 7; ++nf)
        acc[mf][nf] = __builtin_amdgcn_mfma_f32_16x16x32_bf16(af[mf], bfr[nf], acc[mf][nf], 0, 0, 0);
  }
#undef SC_LOAD
#undef SC_STORE

  // epilogue: per-lane partial row sums over this wave's 112 cols
  float s[2][4];
#pragma unroll
  for (int mf = 0; mf < 2; ++mf)
#pragma unroll
    for (int r = 0; r < 4; ++r) s[mf][r] = 0.f;

#pragma unroll
  for (int mf = 0; mf < 2; ++mf) {
    const int rbase = wr * 32 + mf * 16 + q * 4;
#pragma unroll
    for (int nf = 0; nf < 7; ++nf) {
      const int col = wc * 112 + nf * 16 + lc;
      const float bp = bpad[col], wp = wpad[col];
#pragma unroll
      for (int r = 0; r < 4; ++r)
        s[mf][r] += tanhf(acc[mf][nf][r] + bp + hhs[rbase + r]) * wp;
    }
  }
#pragma unroll
  for (int mask = 1; mask <= 8; mask <<= 1) {
#pragma unroll
    for (int mf = 0; mf < 2; ++mf)
#pragma unroll
      for (int r = 0; r < 4; ++r) s[mf][r] += __shfl_xor(s[mf][r], mask);
  }
  if (lc == 0) {
#pragma unroll
    for (int mf = 0; mf < 2; ++mf)
#pragma unroll
      for (int r = 0; r < 4; ++r)
        sred[wc][wr * 32 + mf * 16 + q * 4 + r] = s[mf][r];
  }
  __syncthreads();
  if (t < 64) score[m0 + t] = sred[0][t] + sred[1][t] + d2db[0];
}

// softmax over a (196) per batch row, in place
__global__ __launch_bounds__(256) void k_softmax_att(float* __restrict__ sc)
{
  __shared__ float red[256];
  const int b = blockIdx.x, t = threadIdx.x;
  float v = (t < A_) ? sc[b*A_ + t] : -INFINITY;
  red[t] = v; __syncthreads();
  for (int s = 128; s > 0; s >>= 1) { if (t < s) red[t] = fmaxf(red[t], red[t+s]); __syncthreads(); }
  const float mx = red[0]; __syncthreads();
  const float e = (t < A_) ? expf(v - mx) : 0.f;
  red[t] = e; __syncthreads();
  for (int s = 128; s > 0; s >>= 1) { if (t < s) red[t] += red[t+s]; __syncthreads(); }
  if (t < A_) sc[b*A_ + t] = e / red[0];
}

// att_res[b,r] = sum_a att[b,a,r] * w[b,a]
__global__ __launch_bounds__(256) void k_attres(
    const float* __restrict__ att, const float* __restrict__ w, float* __restrict__ out)
{
  __shared__ float wl[A_];
  const int b = blockIdx.x, t = threadIdx.x;
  if (t < A_) wl[t] = w[b*A_ + t];
  __syncthreads();
  const int r = blockIdx.y * 256 + t;
  const float* ap = att + (size_t)b * A_ * R_ + r;
  float acc = 0.f;
#pragma unroll 4
  for (int a = 0; a < A_; ++a) acc = fmaf(ap[(size_t)a * R_], wl[a], acc);
  out[b * R_ + r] = acc;
}

// ---------------------------------------------------------------------------
// LSTM gate GEMM via MFMA: sums[p,b,g] over K=1536 (xt|ph|ar segments).
// M_tile=64 (b), N_tile=128 (p*2048+g), grid (4,48). Waves 2x2.
// ---------------------------------------------------------------------------
__global__ __launch_bounds__(256) void k_lstm_mfma(
    const float* __restrict__ xt, const float* __restrict__ ph, const float* __restrict__ ar,
    const short* __restrict__ wi, const short* __restrict__ wh, const short* __restrict__ wa,
    int layer, float* __restrict__ sums)
{
  __shared__ __align__(16) short As[4 * 64 * 8];    // 4 KiB
  __shared__ __align__(16) short Bs[4 * 128 * 8];   // 8 KiB

  const int t   = threadIdx.x;
  const int m0  = blockIdx.x * 64;
  const int n0  = blockIdx.y * 128;
  const int wid = t >> 6, l = t & 63;
  const int wr  = wid >> 1, wc = wid & 1;
  const int q   = l >> 4, lc = l & 15;

  f32x4 acc[2][4];
#pragma unroll
  for (int i = 0; i < 2; ++i)
#pragma unroll
    for (int j = 0; j < 4; ++j) acc[i][j] = (f32x4){0.f, 0.f, 0.f, 0.f};

  const int s_row = t >> 2, s_kb = t & 3;
  const size_t wrow0 = ((size_t)layer * 6144 + n0) * R_;

  float4 ra0, ra1;
  bf16x8 rb0, rb1;

#define LS_LOAD(ks) {                                                   \
    const int seg = (ks) >> 4;                                          \
    const int kk  = ((ks) & 15) * 32;                                   \
    const float* asel = (seg == 0) ? xt : (seg == 1) ? ph : ar;         \
    const float* ap = asel + (size_t)(m0 + s_row) * R_ + kk + s_kb * 8; \
    ra0 = *(const float4*)ap;                                           \
    ra1 = *(const float4*)(ap + 4);                                     \
    const short* wsel = (seg == 0) ? wi : (seg == 1) ? wh : wa;         \
    const short* bp0 = wsel + wrow0 + (size_t)(s_row      ) * R_ + kk + s_kb * 8; \
    const short* bp1 = wsel + wrow0 + (size_t)(s_row +  64) * R_ + kk + s_kb * 8; \
    rb0 = *(const bf16x8*)bp0;                                          \
    rb1 = *(const bf16x8*)bp1;                                          \
  }
#define LS_STORE() {                                                    \
    *(bf16x8*)&As[s_kb * 512  + s_row * 8] = cvt8(ra0, ra1);            \
    *(bf16x8*)&Bs[s_kb * 1024 + (s_row      ) * 8] = rb0;               \
    *(bf16x8*)&Bs[s_kb * 1024 + (s_row + 64) * 8] = rb1;                \
  }

  LS_LOAD(0);
  for (int ks = 0; ks < 48; ++ks) {
    __syncthreads();
    LS_STORE();
    __syncthreads();
    if (ks < 47) LS_LOAD(ks + 1);
    bf16x8 af[2], bfr[4];
#pragma unroll
    for (int mf = 0; mf < 2; ++mf) {
      const int row = wr * 32 + mf * 16 + lc;
      af[mf] = *(const bf16x8*)&As[q * 512 + row * 8];
    }
#pragma unroll
    for (int nf = 0; nf < 4; ++nf) {
      const int n = wc * 64 + nf * 16 + lc;
      bfr[nf] = *(const bf16x8*)&Bs[q * 1024 + n * 8];
    }
#pragma unroll
    for (int mf = 0; mf < 2; ++mf)
#pragma unroll
      for (int nf = 0; nf < 4; ++nf)
        acc[mf][nf] = __builtin_amdgcn_mfma_f32_16x16x32_bf16(af[mf], bfr[nf], acc[mf][nf], 0, 0, 0);
  }
#undef LS_LOAD
#undef LS_STORE

#pragma unroll
  for (int mf = 0; mf < 2; ++mf) {
#pragma unroll
    for (int nf = 0; nf < 4; ++nf) {
      const int col = n0 + wc * 64 + nf * 16 + lc;
      const int p = col >> 11, g = col & 2047;
#pragma unroll
      for (int r = 0; r < 4; ++r) {
        const int b = m0 + wr * 32 + mf * 16 + q * 4 + r;
        sums[((size_t)p * B_ + b) * (size_t)G4 + g] = acc[mf][nf][r];
      }
    }
  }
}

__global__ __launch_bounds__(256) void k_lstm_elem(
    const float* __restrict__ sums,
    const float* __restrict__ i2hb, const float* __restrict__ h2hb, const float* __restrict__ a2hb,
    const float* __restrict__ prev_c, int layer,
    float* __restrict__ out_c, float* __restrict__ next_h)
{
  const int idx = blockIdx.x * 256 + threadIdx.x;  // 0..131071
  const int b = idx >> 9, r = idx & 511;
  const size_t boff = (size_t)layer * P_ * G4;
  const float pc = prev_c[idx];
  float aC = 0.f, aH = 0.f;
#pragma unroll
  for (int p = 0; p < P_; ++p) {
    const float* sp = sums + ((size_t)p * B_ + b) * (size_t)G4;
    const float* b1 = i2hb + boff + p * G4;
    const float* b2 = h2hb + boff + p * G4;
    const float* b3 = a2hb + boff + p * G4;
    const float gi = sp[r]      + b1[r]      + b2[r]      + b3[r];
    const float gf = sp[r+512]  + b1[r+512]  + b2[r+512]  + b3[r+512];
    const float go = sp[r+1024] + b1[r+1024] + b2[r+1024] + b3[r+1024];
    const float gt = sp[r+1536] + b1[r+1536] + b2[r+1536] + b3[r+1536];
    const float ig = 1.f / (1.f + expf(-gi));
    const float fg = 1.f / (1.f + expf(-gf));
    const float og = 1.f / (1.f + expf(-go));
    const float it = tanhf(gt);
    const float nc = fg * pc + ig * it;
    const float nh = og * tanhf(nc);
    aC += nc; aH += nh;
  }
  out_c[idx]  = aC * (1.f/3.f);
  next_h[idx] = aH * (1.f/3.f);
}

__global__ __launch_bounds__(256) void k_toph(
    const float* __restrict__ attres, const float* __restrict__ nh, const float* __restrict__ x,
    float* __restrict__ out_slot, float* __restrict__ toph, float* __restrict__ xt_next, int make_xt)
{
  const int idx = blockIdx.x * 256 + threadIdx.x;
  const float v = attres[idx] + nh[idx];
  out_slot[idx] = v;
  toph[idx] = v;
  if (make_xt) xt_next[idx] = x[idx] + v;
}

// ---------------------------------------------------------------------------
// Projection GEMM via MFMA: logits[b, v] = toph @ proj_w^T + pb.
// M_tile=64, N_tile=128, grid (4,75); N padded 9487 -> 9600.
// ---------------------------------------------------------------------------
__global__ __launch_bounds__(256) void k_proj_mfma(
    const float* __restrict__ th, const short* __restrict__ pwb,
    const float* __restrict__ pb, float* __restrict__ logits)
{
  __shared__ __align__(16) short As[4 * 64 * 8];
  __shared__ __align__(16) short Bs[4 * 128 * 8];

  const int t   = threadIdx.x;
  const int m0  = blockIdx.x * 64;
  const int n0  = blockIdx.y * 128;
  const int wid = t >> 6, l = t & 63;
  const int wr  = wid >> 1, wc = wid & 1;
  const int q   = l >> 4, lc = l & 15;

  f32x4 acc[2][4];
#pragma unroll
  for (int i = 0; i < 2; ++i)
#pragma unroll
    for (int j = 0; j < 4; ++j) acc[i][j] = (f32x4){0.f, 0.f, 0.f, 0.f};

  const int s_row = t >> 2, s_kb = t & 3;
  const int ng0 = n0 + s_row, ng1 = n0 + s_row + 64;

  float4 ra0, ra1;
  bf16x8 rb0, rb1;

#define PJ_LOAD(ks) {                                                   \
    const int kk = (ks) * 32;                                           \
    const float* ap = th + (size_t)(m0 + s_row) * R_ + kk + s_kb * 8;   \
    ra0 = *(const float4*)ap;                                           \
    ra1 = *(const float4*)(ap + 4);                                     \
    if (ng0 < V_) rb0 = *(const bf16x8*)(pwb + (size_t)ng0 * R_ + kk + s_kb * 8); \
    else          rb0 = (bf16x8){0,0,0,0,0,0,0,0};                      \
    if (ng1 < V_) rb1 = *(const bf16x8*)(pwb + (size_t)ng1 * R_ + kk + s_kb * 8); \
    else          rb1 = (bf16x8){0,0,0,0,0,0,0,0};                      \
  }
#define PJ_STORE() {                                                    \
    *(bf16x8*)&As[s_kb * 512  + s_row * 8] = cvt8(ra0, ra1);            \
    *(bf16x8*)&Bs[s_kb * 1024 + (s_row      ) * 8] = rb0;               \
    *(bf16x8*)&Bs[s_kb * 1024 + (s_row + 64) * 8] = rb1;                \
  }

  PJ_LOAD(0);
  for (int ks = 0; ks < 16; ++ks) {
    __syncthreads();
    PJ_STORE();
    __syncthreads();
    if (ks < 15) PJ_LOAD(ks + 1);
    bf16x8 af[2], bfr[4];
#pragma unroll
    for (int mf = 0; mf < 2; ++mf) {
      const int row = wr * 32 + mf * 16 + lc;
      af[mf] = *(const bf16x8*)&As[q * 512 + row * 8];
    }
#pragma unroll
    for (int nf = 0; nf < 4; ++nf) {
      const int n = wc * 64 + nf * 16 + lc;
      bfr[nf] = *(const bf16x8*)&Bs[q * 1024 + n * 8];
    }
#pragma unroll
    for (int mf = 0; mf < 2; ++mf)
#pragma unroll
      for (int nf = 0; nf < 4; ++nf)
        acc[mf][nf] = __builtin_amdgcn_mfma_f32_16x16x32_bf16(af[mf], bfr[nf], acc[mf][nf], 0, 0, 0);
  }
#undef PJ_LOAD
#undef PJ_STORE

#pragma unroll
  for (int mf = 0; mf < 2; ++mf) {
#pragma unroll
    for (int nf = 0; nf < 4; ++nf) {
      const int col = n0 + wc * 64 + nf * 16 + lc;
      if (col < V_) {
        const float bias = pb[col];
#pragma unroll
        for (int r = 0; r < 4; ++r) {
          const int b = m0 + wr * 32 + mf * 16 + q * 4 + r;
          logits[(size_t)b * V_ + col] = acc[mf][nf][r] + bias;
        }
      }
    }
  }
}

__global__ __launch_bounds__(256) void k_logsoftmax(
    const float* __restrict__ logits, float* __restrict__ out)
{
  __shared__ float red[256];
  const int b = blockIdx.x, t = threadIdx.x;
  const float* lp = logits + (size_t)b * V_;
  float mx = -INFINITY;
  for (int n = t; n < V_; n += 256) mx = fmaxf(mx, lp[n]);
  red[t] = mx; __syncthreads();
  for (int s = 128; s > 0; s >>= 1) { if (t < s) red[t] = fmaxf(red[t], red[t+s]); __syncthreads(); }
  mx = red[0]; __syncthreads();
  float sm = 0.f;
  for (int n = t; n < V_; n += 256) sm += expf(lp[n] - mx);
  red[t] = sm; __syncthreads();
  for (int s = 128; s > 0; s >>= 1) { if (t < s) red[t] += red[t+s]; __syncthreads(); }
  const float lse = mx + logf(red[0]);
  float* op = out + (size_t)b * V_;
  for (int n = t; n < V_; n += 256) op[n] = lp[n] - lse;
}

extern "C" void kernel_launch(void* const* d_in, const int* in_sizes, int n_in,
                              void* d_out, int out_size, void* d_ws, size_t ws_size,
                              hipStream_t stream)
{
  const float* x      = (const float*)d_in[0];
  const float* att    = (const float*)d_in[1];
  const float* inputs = (const float*)d_in[2];
  const float* i2hw   = (const float*)d_in[3];
  const float* i2hb   = (const float*)d_in[4];
  const float* h2hw   = (const float*)d_in[5];
  const float* h2hb   = (const float*)d_in[6];
  const float* a2hw   = (const float*)d_in[7];
  const float* a2hb   = (const float*)d_in[8];
  const float* a2aw   = (const float*)d_in[9];
  const float* a2ab   = (const float*)d_in[10];
  const float* h2aw   = (const float*)d_in[11];
  const float* h2ab   = (const float*)d_in[12];
  const float* d2dw   = (const float*)d_in[13];
  const float* d2db   = (const float*)d_in[14];
  const float* pw     = (const float*)d_in[15];
  const float* pb     = (const float*)d_in[16];
  float* out = (float*)d_out;
  float* ws  = (float*)d_ws;

  // fp32 scratch (float offsets)
  float* w_score  = ws + 0;        // 50176
  float* w_hh     = ws + 51200;    // 50176
  float* w_attres = ws + 102400;   // 131072
  float* w_xt     = ws + 233472;   // 131072
  float* w_nexth  = ws + 364544;   // 131072
  float* w_toph   = ws + 495616;   // 131072
  float* w_sums   = ws + 626688;   // 1572864
  float* w_logits = ws + 2199552;  // 2428672 -> ends 4628224

  // bf16 weight copies
  short* bfbase = (short*)(ws + 4628480);          // 16B aligned
  short* aw_bf  = bfbase;                          // 2*2*196*512   = 401408
  short* wi_bf  = bfbase + 401408;                 // 2*3*2048*512  = 6291456
  short* wh_bf  = bfbase + 6692864;                // 6291456
  short* wa_bf  = bfbase + 12984320;               // 6291456
  short* pw_bf  = bfbase + 19275776;               // 9487*512      = 4857344
  // total: ~18.5 MB fp32 + ~48.3 MB bf16

  // ---- weight conversions (every launch; inputs-only dependence) ----
  k_cvt<<<196,  256, 0, stream>>>(a2aw, aw_bf, 401408);
  k_cvt<<<3072, 256, 0, stream>>>(i2hw, wi_bf, 6291456);
  k_cvt<<<3072, 256, 0, stream>>>(h2hw, wh_bf, 6291456);
  k_cvt<<<3072, 256, 0, stream>>>(a2hw, wa_bf, 6291456);
  k_cvt<<<2372, 256, 0, stream>>>(pw,   pw_bf, 4857344);

  const float* cur_x = x;
  for (int i = 0; i < L_; ++i) {
    const float* prev_c = inputs + (size_t)(2*i)   * BR;
    const float* prev_h = inputs + (size_t)(2*i+1) * BR;

    // --- att_res0 = soft_att(att, prev_h, weights[i,0]) ---
    {
      const int idx = i*2 + 0;
      k_hh<<<784, 256, 0, stream>>>(prev_h, h2aw + (size_t)idx*A_*R_, h2ab + (size_t)idx*A_, w_hh);
      k_score_mfma<<<784, 256, 0, stream>>>(att, aw_bf + (size_t)idx*A_*R_,
          a2ab + (size_t)idx*A_, d2dw + (size_t)idx*A_, d2db + idx, w_hh, w_score);
      k_softmax_att<<<B_, 256, 0, stream>>>(w_score);
      k_attres<<<dim3(B_, 2), 256, 0, stream>>>(att, w_score, w_attres);
    }

    // --- LSTM ---
    k_lstm_mfma<<<dim3(4, 48), 256, 0, stream>>>(cur_x, prev_h, w_attres,
                                                 wi_bf, wh_bf, wa_bf, i, w_sums);
    k_lstm_elem<<<512, 256, 0, stream>>>(w_sums, i2hb, h2hb, a2hb, prev_c, i,
                                         out + (size_t)(2*i) * BR, w_nexth);

    // --- att_res1 = soft_att(att, next_h, weights[i,1]) ---
    {
      const int idx = i*2 + 1;
      k_hh<<<784, 256, 0, stream>>>(w_nexth, h2aw + (size_t)idx*A_*R_, h2ab + (size_t)idx*A_, w_hh);
      k_score_mfma<<<784, 256, 0, stream>>>(att, aw_bf + (size_t)idx*A_*R_,
          a2ab + (size_t)idx*A_, d2dw + (size_t)idx*A_, d2db + idx, w_hh, w_score);
      k_softmax_att<<<B_, 256, 0, stream>>>(w_score);
      k_attres<<<dim3(B_, 2), 256, 0, stream>>>(att, w_score, w_attres);
    }

    // --- top_h = att_res1 + next_h ; xt for next layer = x + top_h ---
    k_toph<<<512, 256, 0, stream>>>(w_attres, w_nexth, x,
                                    out + (size_t)(2*i+1) * BR, w_toph, w_xt,
                                    (i == 0) ? 1 : 0);
    cur_x = w_xt;
  }

  k_proj_mfma<<<dim3(4, 75), 256, 0, stream>>>(w_toph, pw_bf, pb, w_logits);
  k_logsoftmax<<<B_, 256, 0, stream>>>(w_logits, out + (size_t)4 * BR);
}

// Round 4
// 747.003 us; speedup vs baseline: 2.2602x; 1.0068x over previous
//
#include <hip/hip_runtime.h>
#include <hip/hip_bf16.h>
#include <math.h>

#define L_ 2
#define P_ 3
#define R_ 512
#define A_ 196
#define V_ 9487
#define B_ 256
#define BR (B_*R_)   /* 131072 */
#define G4 (4*R_)    /* 2048 */

typedef short bf16x8 __attribute__((ext_vector_type(8)));
typedef float f32x4  __attribute__((ext_vector_type(4)));
typedef unsigned int u32;

static __device__ __forceinline__ unsigned short f2b(float f){
  u32 u = __builtin_bit_cast(u32, f);
  u += 0x7fffu + ((u >> 16) & 1u);
  return (unsigned short)(u >> 16);
}
static __device__ __forceinline__ float b2f(short s){
  u32 u = ((u32)(unsigned short)s) << 16;
  return __builtin_bit_cast(float, u);
}
static __device__ __forceinline__ bf16x8 cvt8(float4 a, float4 b){
  bf16x8 r;
  r[0]=(short)f2b(a.x); r[1]=(short)f2b(a.y); r[2]=(short)f2b(a.z); r[3]=(short)f2b(a.w);
  r[4]=(short)f2b(b.x); r[5]=(short)f2b(b.y); r[6]=(short)f2b(b.z); r[7]=(short)f2b(b.w);
  return r;
}

// async global->LDS, 16B per lane; LDS dest must be wave-uniform base (+lane*16 implied)
static __device__ __forceinline__ void gld16(const void* g, void* l){
  __builtin_amdgcn_global_load_lds(
      (const __attribute__((address_space(1))) u32*)g,
      (__attribute__((address_space(3))) u32*)l, 16, 0, 0);
}

// bank swizzle selector for [row][slot] k-chunk layout: 2-way max on ds_read_b128
#define SW(x) ((((x)&3) ^ (((x)>>2)&3)))

// ---------------------------------------------------------------------------
// fp32 -> bf16 elementwise (n multiple of 8)
// ---------------------------------------------------------------------------
__global__ __launch_bounds__(256) void k_cvt(const float* __restrict__ src,
                                             short* __restrict__ dst, int n)
{
  const int c = blockIdx.x * 256 + threadIdx.x;
  const int base = c * 8;
  if (base >= n) return;
  float4 a = *(const float4*)(src + base);
  float4 b = *(const float4*)(src + base + 4);
  *(bf16x8*)(dst + base) = cvt8(a, b);
}

// a2a_w [4][196][512] -> padded bf16 [4][256][512], rows 196..255 zeroed
__global__ __launch_bounds__(256) void k_cvt_pad_aw(const float* __restrict__ src,
                                                    short* __restrict__ dst)
{
  const int idx8 = (blockIdx.x * 256 + threadIdx.x) * 8;   // < 4*256*512 = 524288
  const int g   = idx8 >> 17;
  const int rem = idx8 & 131071;
  const int row = rem >> 9;
  const int k   = rem & 511;
  bf16x8 v;
  if (row < A_) {
    const float* sp = src + ((size_t)g * A_ + row) * R_ + k;
    v = cvt8(*(const float4*)sp, *(const float4*)(sp + 4));
  } else {
    v = (bf16x8){0,0,0,0,0,0,0,0};
  }
  *(bf16x8*)(dst + idx8) = v;
}

// hh[m] = h[b]·h2aw[a] + h2ab[a],  m = b*196 + a ; 64 rows per block
__global__ __launch_bounds__(256) void k_hh(
    const float* __restrict__ h, const float* __restrict__ hw,
    const float* __restrict__ hb, float* __restrict__ out)
{
  __shared__ float hred[64][5];
  const int t = threadIdx.x;
  const int row = blockIdx.x * 64 + (t >> 2);
  const int seg = t & 3;
  const int b = row / A_;
  const int a = row - b * A_;
  const float* hp = h  + (size_t)b * R_ + seg * 128;
  const float* wp = hw + (size_t)a * R_ + seg * 128;
  float p = 0.f;
#pragma unroll
  for (int k = 0; k < 128; k += 4) {
    float4 a4 = *(const float4*)(hp + k);
    float4 b4 = *(const float4*)(wp + k);
    p = fmaf(a4.x, b4.x, p); p = fmaf(a4.y, b4.y, p);
    p = fmaf(a4.z, b4.z, p); p = fmaf(a4.w, b4.w, p);
  }
  hred[t >> 2][seg] = p;
  __syncthreads();
  if (t < 64) {
    const int m = blockIdx.x * 64 + t;
    const int b2 = m / A_;
    const int a2 = m - b2 * A_;
    out[m] = hred[t][0] + hred[t][1] + hred[t][2] + hred[t][3] + hb[a2];
  }
}

// ---------------------------------------------------------------------------
// Score v2: double-buffered global_load_lds pipeline.
// C[m,n] = att_bf[m,:] @ wbf[n,:]^T  (M=64/block, Npad=256, K=512, KT=32)
// score[m] = sum_n tanh(C + bpad[n] + hh[m]) * wpad[n] + d2db
// LDS cells: A [row(64)][slot(4)] , B [n(256)][slot(4)], cell = 8 shorts (16B);
// slot holds k-chunk kb = slot ^ SW(row|n)  (bank de-conflict via source perm).
// 4 waves 2(M-half)x2(N-half); per wave per K-step: 2 A-frags, 8 B-frags, 16 MFMA.
// ---------------------------------------------------------------------------
__global__ __launch_bounds__(256) void k_score_mfma(
    const short* __restrict__ att_bf, const short* __restrict__ wbf,
    const float* __restrict__ a2ab, const float* __restrict__ d2dw,
    const float* __restrict__ d2db, const float* __restrict__ hh,
    float* __restrict__ score)
{
  __shared__ __align__(16) short As[2][256 * 8];    // 2 x 4 KiB
  __shared__ __align__(16) short Bs[2][1024 * 8];   // 2 x 16 KiB
  __shared__ float wpad[256], bpad[256], hhs[64], sred[2][64];

  const int t   = threadIdx.x;
  const int m0  = blockIdx.x * 64;
  const int wid = t >> 6, l = t & 63;
  const int wr  = wid >> 1, wc = wid & 1;
  const int q   = l >> 4, lc = l & 15;

  wpad[t] = (t < A_) ? d2dw[t] : 0.f;
  bpad[t] = (t < A_) ? a2ab[t] : 0.f;
  if (t < 64) hhs[t] = hh[m0 + t];

  f32x4 acc[2][8];
#pragma unroll
  for (int i = 0; i < 2; ++i)
#pragma unroll
    for (int j = 0; j < 8; ++j) acc[i][j] = (f32x4){0.f, 0.f, 0.f, 0.f};

  // per-lane staging coords
  const int a_row  = t >> 2;                 // 0..63
  const int a_kb   = (t & 3) ^ SW(a_row);    // permuted k-chunk
  const short* a_g = att_bf + (size_t)(m0 + a_row) * R_ + a_kb * 8;
  int b_n[4], b_kb[4];
#pragma unroll
  for (int j = 0; j < 4; ++j) {
    b_n[j]  = j * 64 + (t >> 2);
    b_kb[j] = (t & 3) ^ SW(b_n[j]);
  }

#define STAGE(bufi, kz) {                                                 \
    gld16((const void*)(a_g + (kz)), (void*)&As[bufi][wid * 512]);        \
    _Pragma("unroll")                                                     \
    for (int j = 0; j < 4; ++j)                                           \
      gld16((const void*)(wbf + (size_t)b_n[j] * R_ + (kz) + b_kb[j] * 8),\
            (void*)&Bs[bufi][j * 2048 + wid * 512]);                      \
  }

  STAGE(0, 0);
  __syncthreads();

  for (int ks = 0; ks < 16; ++ks) {
    const int cur = ks & 1;
    if (ks < 15) STAGE(cur ^ 1, (ks + 1) * 32);
    bf16x8 af[2], bfr[8];
#pragma unroll
    for (int mf = 0; mf < 2; ++mf) {
      const int row = wr * 32 + mf * 16 + lc;
      af[mf] = *(const bf16x8*)&As[cur][(row * 4 + (q ^ SW(row))) * 8];
    }
#pragma unroll
    for (int nf = 0; nf < 8; ++nf) {
      const int n = wc * 128 + nf * 16 + lc;
      bfr[nf] = *(const bf16x8*)&Bs[cur][(n * 4 + (q ^ SW(n))) * 8];
    }
#pragma unroll
    for (int mf = 0; mf < 2; ++mf)
#pragma unroll
      for (int nf = 0; nf < 8; ++nf)
        acc[mf][nf] = __builtin_amdgcn_mfma_f32_16x16x32_bf16(af[mf], bfr[nf], acc[mf][nf], 0, 0, 0);
    __syncthreads();   // drains next-tile DMA + protects buffer reuse
  }
#undef STAGE

  // epilogue: per-lane partial row sums over this wave's 128 cols
  float s[2][4];
#pragma unroll
  for (int mf = 0; mf < 2; ++mf)
#pragma unroll
    for (int r = 0; r < 4; ++r) s[mf][r] = 0.f;

#pragma unroll
  for (int mf = 0; mf < 2; ++mf) {
    const int rbase = wr * 32 + mf * 16 + q * 4;
#pragma unroll
    for (int nf = 0; nf < 8; ++nf) {
      const int col = wc * 128 + nf * 16 + lc;
      const float bp = bpad[col], wp = wpad[col];
#pragma unroll
      for (int r = 0; r < 4; ++r)
        s[mf][r] += tanhf(acc[mf][nf][r] + bp + hhs[rbase + r]) * wp;
    }
  }
#pragma unroll
  for (int mask = 1; mask <= 8; mask <<= 1) {
#pragma unroll
    for (int mf = 0; mf < 2; ++mf)
#pragma unroll
      for (int r = 0; r < 4; ++r) s[mf][r] += __shfl_xor(s[mf][r], mask);
  }
  if (lc == 0) {
#pragma unroll
    for (int mf = 0; mf < 2; ++mf)
#pragma unroll
      for (int r = 0; r < 4; ++r)
        sred[wc][wr * 32 + mf * 16 + q * 4 + r] = s[mf][r];
  }
  __syncthreads();
  if (t < 64) score[m0 + t] = sred[0][t] + sred[1][t] + d2db[0];
}

// ---------------------------------------------------------------------------
// Fused softmax(196) + att_res: out[b,r] = sum_a att[b,a,r]*softmax(score)[b,a]
// grid (B, 2): each block recomputes the (cheap) softmax, handles 256 r's.
// ---------------------------------------------------------------------------
__global__ __launch_bounds__(256) void k_smax_attres(
    const float* __restrict__ sc, const short* __restrict__ att_bf,
    float* __restrict__ out)
{
  __shared__ float red[256];
  __shared__ float wl[256];
  const int b = blockIdx.x, t = threadIdx.x;
  const float v = (t < A_) ? sc[b * A_ + t] : -INFINITY;
  red[t] = v; __syncthreads();
  for (int s = 128; s > 0; s >>= 1) { if (t < s) red[t] = fmaxf(red[t], red[t+s]); __syncthreads(); }
  const float mx = red[0]; __syncthreads();
  const float e = (t < A_) ? expf(v - mx) : 0.f;
  red[t] = e; __syncthreads();
  for (int s = 128; s > 0; s >>= 1) { if (t < s) red[t] += red[t+s]; __syncthreads(); }
  wl[t] = e / red[0];
  __syncthreads();

  const int r = blockIdx.y * 256 + t;
  const short* ap = att_bf + (size_t)b * A_ * R_ + r;
  float acc = 0.f;
  int a = 0;
#pragma unroll 4
  for (; a < 196; ++a) acc = fmaf(b2f(ap[(size_t)a * R_]), wl[a], acc);
  out[b * R_ + r] = acc;
}

// ---------------------------------------------------------------------------
// LSTM gate GEMM via MFMA (unchanged R3): sums[p,b,g] over K=1536.
// ---------------------------------------------------------------------------
__global__ __launch_bounds__(256) void k_lstm_mfma(
    const float* __restrict__ xt, const float* __restrict__ ph, const float* __restrict__ ar,
    const short* __restrict__ wi, const short* __restrict__ wh, const short* __restrict__ wa,
    int layer, float* __restrict__ sums)
{
  __shared__ __align__(16) short As[4 * 64 * 8];
  __shared__ __align__(16) short Bs[4 * 128 * 8];

  const int t   = threadIdx.x;
  const int m0  = blockIdx.x * 64;
  const int n0  = blockIdx.y * 128;
  const int wid = t >> 6, l = t & 63;
  const int wr  = wid >> 1, wc = wid & 1;
  const int q   = l >> 4, lc = l & 15;

  f32x4 acc[2][4];
#pragma unroll
  for (int i = 0; i < 2; ++i)
#pragma unroll
    for (int j = 0; j < 4; ++j) acc[i][j] = (f32x4){0.f, 0.f, 0.f, 0.f};

  const int s_row = t >> 2, s_kb = t & 3;
  const size_t wrow0 = ((size_t)layer * 6144 + n0) * R_;

  float4 ra0, ra1;
  bf16x8 rb0, rb1;

#define LS_LOAD(ks) {                                                   \
    const int seg = (ks) >> 4;                                          \
    const int kk  = ((ks) & 15) * 32;                                   \
    const float* asel = (seg == 0) ? xt : (seg == 1) ? ph : ar;         \
    const float* ap = asel + (size_t)(m0 + s_row) * R_ + kk + s_kb * 8; \
    ra0 = *(const float4*)ap;                                           \
    ra1 = *(const float4*)(ap + 4);                                     \
    const short* wsel = (seg == 0) ? wi : (seg == 1) ? wh : wa;         \
    const short* bp0 = wsel + wrow0 + (size_t)(s_row      ) * R_ + kk + s_kb * 8; \
    const short* bp1 = wsel + wrow0 + (size_t)(s_row +  64) * R_ + kk + s_kb * 8; \
    rb0 = *(const bf16x8*)bp0;                                          \
    rb1 = *(const bf16x8*)bp1;                                          \
  }
#define LS_STORE() {                                                    \
    *(bf16x8*)&As[s_kb * 512  + s_row * 8] = cvt8(ra0, ra1);            \
    *(bf16x8*)&Bs[s_kb * 1024 + (s_row      ) * 8] = rb0;               \
    *(bf16x8*)&Bs[s_kb * 1024 + (s_row + 64) * 8] = rb1;                \
  }

  LS_LOAD(0);
  for (int ks = 0; ks < 48; ++ks) {
    __syncthreads();
    LS_STORE();
    __syncthreads();
    if (ks < 47) LS_LOAD(ks + 1);
    bf16x8 af[2], bfr[4];
#pragma unroll
    for (int mf = 0; mf < 2; ++mf) {
      const int row = wr * 32 + mf * 16 + lc;
      af[mf] = *(const bf16x8*)&As[q * 512 + row * 8];
    }
#pragma unroll
    for (int nf = 0; nf < 4; ++nf) {
      const int n = wc * 64 + nf * 16 + lc;
      bfr[nf] = *(const bf16x8*)&Bs[q * 1024 + n * 8];
    }
#pragma unroll
    for (int mf = 0; mf < 2; ++mf)
#pragma unroll
      for (int nf = 0; nf < 4; ++nf)
        acc[mf][nf] = __builtin_amdgcn_mfma_f32_16x16x32_bf16(af[mf], bfr[nf], acc[mf][nf], 0, 0, 0);
  }
#undef LS_LOAD
#undef LS_STORE

#pragma unroll
  for (int mf = 0; mf < 2; ++mf) {
#pragma unroll
    for (int nf = 0; nf < 4; ++nf) {
      const int col = n0 + wc * 64 + nf * 16 + lc;
      const int p = col >> 11, g = col & 2047;
#pragma unroll
      for (int r = 0; r < 4; ++r) {
        const int b = m0 + wr * 32 + mf * 16 + q * 4 + r;
        sums[((size_t)p * B_ + b) * (size_t)G4 + g] = acc[mf][nf][r];
      }
    }
  }
}

__global__ __launch_bounds__(256) void k_lstm_elem(
    const float* __restrict__ sums,
    const float* __restrict__ i2hb, const float* __restrict__ h2hb, const float* __restrict__ a2hb,
    const float* __restrict__ prev_c, int layer,
    float* __restrict__ out_c, float* __restrict__ next_h)
{
  const int idx = blockIdx.x * 256 + threadIdx.x;
  const int b = idx >> 9, r = idx & 511;
  const size_t boff = (size_t)layer * P_ * G4;
  const float pc = prev_c[idx];
  float aC = 0.f, aH = 0.f;
#pragma unroll
  for (int p = 0; p < P_; ++p) {
    const float* sp = sums + ((size_t)p * B_ + b) * (size_t)G4;
    const float* b1 = i2hb + boff + p * G4;
    const float* b2 = h2hb + boff + p * G4;
    const float* b3 = a2hb + boff + p * G4;
    const float gi = sp[r]      + b1[r]      + b2[r]      + b3[r];
    const float gf = sp[r+512]  + b1[r+512]  + b2[r+512]  + b3[r+512];
    const float go = sp[r+1024] + b1[r+1024] + b2[r+1024] + b3[r+1024];
    const float gt = sp[r+1536] + b1[r+1536] + b2[r+1536] + b3[r+1536];
    const float ig = 1.f / (1.f + expf(-gi));
    const float fg = 1.f / (1.f + expf(-gf));
    const float og = 1.f / (1.f + expf(-go));
    const float it = tanhf(gt);
    const float nc = fg * pc + ig * it;
    const float nh = og * tanhf(nc);
    aC += nc; aH += nh;
  }
  out_c[idx]  = aC * (1.f/3.f);
  next_h[idx] = aH * (1.f/3.f);
}

__global__ __launch_bounds__(256) void k_toph(
    const float* __restrict__ attres, const float* __restrict__ nh, const float* __restrict__ x,
    float* __restrict__ out_slot, float* __restrict__ toph, float* __restrict__ xt_next, int make_xt)
{
  const int idx = blockIdx.x * 256 + threadIdx.x;
  const float v = attres[idx] + nh[idx];
  out_slot[idx] = v;
  toph[idx] = v;
  if (make_xt) xt_next[idx] = x[idx] + v;
}

// ---------------------------------------------------------------------------
// Projection GEMM via MFMA (unchanged R3).
// ---------------------------------------------------------------------------
__global__ __launch_bounds__(256) void k_proj_mfma(
    const float* __restrict__ th, const short* __restrict__ pwb,
    const float* __restrict__ pb, float* __restrict__ logits)
{
  __shared__ __align__(16) short As[4 * 64 * 8];
  __shared__ __align__(16) short Bs[4 * 128 * 8];

  const int t   = threadIdx.x;
  const int m0  = blockIdx.x * 64;
  const int n0  = blockIdx.y * 128;
  const int wid = t >> 6, l = t & 63;
  const int wr  = wid >> 1, wc = wid & 1;
  const int q   = l >> 4, lc = l & 15;

  f32x4 acc[2][4];
#pragma unroll
  for (int i = 0; i < 2; ++i)
#pragma unroll
    for (int j = 0; j < 4; ++j) acc[i][j] = (f32x4){0.f, 0.f, 0.f, 0.f};

  const int s_row = t >> 2, s_kb = t & 3;
  const int ng0 = n0 + s_row, ng1 = n0 + s_row + 64;

  float4 ra0, ra1;
  bf16x8 rb0, rb1;

#define PJ_LOAD(ks) {                                                   \
    const int kk = (ks) * 32;                                           \
    const float* ap = th + (size_t)(m0 + s_row) * R_ + kk + s_kb * 8;   \
    ra0 = *(const float4*)ap;                                           \
    ra1 = *(const float4*)(ap + 4);                                     \
    if (ng0 < V_) rb0 = *(const bf16x8*)(pwb + (size_t)ng0 * R_ + kk + s_kb * 8); \
    else          rb0 = (bf16x8){0,0,0,0,0,0,0,0};                      \
    if (ng1 < V_) rb1 = *(const bf16x8*)(pwb + (size_t)ng1 * R_ + kk + s_kb * 8); \
    else          rb1 = (bf16x8){0,0,0,0,0,0,0,0};                      \
  }
#define PJ_STORE() {                                                    \
    *(bf16x8*)&As[s_kb * 512  + s_row * 8] = cvt8(ra0, ra1);            \
    *(bf16x8*)&Bs[s_kb * 1024 + (s_row      ) * 8] = rb0;               \
    *(bf16x8*)&Bs[s_kb * 1024 + (s_row + 64) * 8] = rb1;                \
  }

  PJ_LOAD(0);
  for (int ks = 0; ks < 16; ++ks) {
    __syncthreads();
    PJ_STORE();
    __syncthreads();
    if (ks < 15) PJ_LOAD(ks + 1);
    bf16x8 af[2], bfr[4];
#pragma unroll
    for (int mf = 0; mf < 2; ++mf) {
      const int row = wr * 32 + mf * 16 + lc;
      af[mf] = *(const bf16x8*)&As[q * 512 + row * 8];
    }
#pragma unroll
    for (int nf = 0; nf < 4; ++nf) {
      const int n = wc * 64 + nf * 16 + lc;
      bfr[nf] = *(const bf16x8*)&Bs[q * 1024 + n * 8];
    }
#pragma unroll
    for (int mf = 0; mf < 2; ++mf)
#pragma unroll
      for (int nf = 0; nf < 4; ++nf)
        acc[mf][nf] = __builtin_amdgcn_mfma_f32_16x16x32_bf16(af[mf], bfr[nf], acc[mf][nf], 0, 0, 0);
  }
#undef PJ_LOAD
#undef PJ_STORE

#pragma unroll
  for (int mf = 0; mf < 2; ++mf) {
#pragma unroll
    for (int nf = 0; nf < 4; ++nf) {
      const int col = n0 + wc * 64 + nf * 16 + lc;
      if (col < V_) {
        const float bias = pb[col];
#pragma unroll
        for (int r = 0; r < 4; ++r) {
          const int b = m0 + wr * 32 + mf * 16 + q * 4 + r;
          logits[(size_t)b * V_ + col] = acc[mf][nf][r] + bias;
        }
      }
    }
  }
}

__global__ __launch_bounds__(256) void k_logsoftmax(
    const float* __restrict__ logits, float* __restrict__ out)
{
  __shared__ float red[256];
  const int b = blockIdx.x, t = threadIdx.x;
  const float* lp = logits + (size_t)b * V_;
  float mx = -INFINITY;
  for (int n = t; n < V_; n += 256) mx = fmaxf(mx, lp[n]);
  red[t] = mx; __syncthreads();
  for (int s = 128; s > 0; s >>= 1) { if (t < s) red[t] = fmaxf(red[t], red[t+s]); __syncthreads(); }
  mx = red[0]; __syncthreads();
  float sm = 0.f;
  for (int n = t; n < V_; n += 256) sm += expf(lp[n] - mx);
  red[t] = sm; __syncthreads();
  for (int s = 128; s > 0; s >>= 1) { if (t < s) red[t] += red[t+s]; __syncthreads(); }
  const float lse = mx + logf(red[0]);
  float* op = out + (size_t)b * V_;
  for (int n = t; n < V_; n += 256) op[n] = lp[n] - lse;
}

extern "C" void kernel_launch(void* const* d_in, const int* in_sizes, int n_in,
                              void* d_out, int out_size, void* d_ws, size_t ws_size,
                              hipStream_t stream)
{
  const float* x      = (const float*)d_in[0];
  const float* att    = (const float*)d_in[1];
  const float* inputs = (const float*)d_in[2];
  const float* i2hw   = (const float*)d_in[3];
  const float* i2hb   = (const float*)d_in[4];
  const float* h2hw   = (const float*)d_in[5];
  const float* h2hb   = (const float*)d_in[6];
  const float* a2hw   = (const float*)d_in[7];
  const float* a2hb   = (const float*)d_in[8];
  const float* a2aw   = (const float*)d_in[9];
  const float* a2ab   = (const float*)d_in[10];
  const float* h2aw   = (const float*)d_in[11];
  const float* h2ab   = (const float*)d_in[12];
  const float* d2dw   = (const float*)d_in[13];
  const float* d2db   = (const float*)d_in[14];
  const float* pw     = (const float*)d_in[15];
  const float* pb     = (const float*)d_in[16];
  float* out = (float*)d_out;
  float* ws  = (float*)d_ws;

  // fp32 scratch (float offsets)
  float* w_score  = ws + 0;        // 50176 (pad 51200)
  float* w_hh     = ws + 51200;    // 50176 (pad 51200)
  float* w_attres = ws + 102400;   // 131072
  float* w_xt     = ws + 233472;   // 131072
  float* w_nexth  = ws + 364544;   // 131072
  float* w_toph   = ws + 495616;   // 131072
  float* w_sums   = ws + 626688;   // 1572864
  float* w_logits = ws + 2199552;  // 2428672 -> ends 4628224

  // bf16 region
  short* bfbase = (short*)(ws + 4628480);
  short* att_bf = bfbase;                       // 50176*512   = 25,690,112
  short* awp_bf = bfbase + 25690112;            // 4*256*512   =    524,288 (padded)
  short* wi_bf  = bfbase + 26214400;            // 6,291,456
  short* wh_bf  = bfbase + 32505856;            // 6,291,456
  short* wa_bf  = bfbase + 38797312;            // 6,291,456
  short* pw_bf  = bfbase + 45088768;            // 4,857,344
  // end: 49,946,112 shorts (~99.9 MB) ; total ws use ~118 MB

  // ---- conversions (every launch) ----
  k_cvt<<<12544, 256, 0, stream>>>(att, att_bf, 25690112);
  k_cvt_pad_aw<<<256, 256, 0, stream>>>(a2aw, awp_bf);
  k_cvt<<<3072, 256, 0, stream>>>(i2hw, wi_bf, 6291456);
  k_cvt<<<3072, 256, 0, stream>>>(h2hw, wh_bf, 6291456);
  k_cvt<<<3072, 256, 0, stream>>>(a2hw, wa_bf, 6291456);
  k_cvt<<<2372, 256, 0, stream>>>(pw,   pw_bf, 4857344);

  const float* cur_x = x;
  for (int i = 0; i < L_; ++i) {
    const float* prev_c = inputs + (size_t)(2*i)   * BR;
    const float* prev_h = inputs + (size_t)(2*i+1) * BR;

    // --- att_res0 = soft_att(att, prev_h, weights[i,0]) ---
    {
      const int idx = i*2 + 0;
      k_hh<<<784, 256, 0, stream>>>(prev_h, h2aw + (size_t)idx*A_*R_, h2ab + (size_t)idx*A_, w_hh);
      k_score_mfma<<<784, 256, 0, stream>>>(att_bf, awp_bf + (size_t)idx*256*R_,
          a2ab + (size_t)idx*A_, d2dw + (size_t)idx*A_, d2db + idx, w_hh, w_score);
      k_smax_attres<<<dim3(B_, 2), 256, 0, stream>>>(w_score, att_bf, w_attres);
    }

    // --- LSTM ---
    k_lstm_mfma<<<dim3(4, 48), 256, 0, stream>>>(cur_x, prev_h, w_attres,
                                                 wi_bf, wh_bf, wa_bf, i, w_sums);
    k_lstm_elem<<<512, 256, 0, stream>>>(w_sums, i2hb, h2hb, a2hb, prev_c, i,
                                         out + (size_t)(2*i) * BR, w_nexth);

    // --- att_res1 = soft_att(att, next_h, weights[i,1]) ---
    {
      const int idx = i*2 + 1;
      k_hh<<<784, 256, 0, stream>>>(w_nexth, h2aw + (size_t)idx*A_*R_, h2ab + (size_t)idx*A_, w_hh);
      k_score_mfma<<<784, 256, 0, stream>>>(att_bf, awp_bf + (size_t)idx*256*R_,
          a2ab + (size_t)idx*A_, d2dw + (size_t)idx*A_, d2db + idx, w_hh, w_score);
      k_smax_attres<<<dim3(B_, 2), 256, 0, stream>>>(w_score, att_bf, w_attres);
    }

    // --- top_h = att_res1 + next_h ; xt for next layer = x + top_h ---
    k_toph<<<512, 256, 0, stream>>>(w_attres, w_nexth, x,
                                    out + (size_t)(2*i+1) * BR, w_toph, w_xt,
                                    (i == 0) ? 1 : 0);
    cur_x = w_xt;
  }

  k_proj_mfma<<<dim3(4, 75), 256, 0, stream>>>(w_toph, pw_bf, pb, w_logits);
  k_logsoftmax<<<B_, 256, 0, stream>>>(w_logits, out + (size_t)4 * BR);
}

// Round 5
// 700.060 us; speedup vs baseline: 2.4118x; 1.0671x over previous
//
#include <hip/hip_runtime.h>
#include <hip/hip_bf16.h>
#include <math.h>

#define L_ 2
#define P_ 3
#define R_ 512
#define A_ 196
#define V_ 9487
#define B_ 256
#define BR (B_*R_)   /* 131072 */
#define G4 (4*R_)    /* 2048 */
#define SSZ 1572864  /* P_*B_*G4 : one lstm partial-sum buffer */

typedef short bf16x8 __attribute__((ext_vector_type(8)));
typedef float f32x4  __attribute__((ext_vector_type(4)));
typedef unsigned int u32;

static __device__ __forceinline__ unsigned short f2b(float f){
  u32 u = __builtin_bit_cast(u32, f);
  u += 0x7fffu + ((u >> 16) & 1u);
  return (unsigned short)(u >> 16);
}
static __device__ __forceinline__ float b2f(unsigned short s){
  u32 u = ((u32)s) << 16;
  return __builtin_bit_cast(float, u);
}
static __device__ __forceinline__ bf16x8 cvt8(float4 a, float4 b){
  bf16x8 r;
  r[0]=(short)f2b(a.x); r[1]=(short)f2b(a.y); r[2]=(short)f2b(a.z); r[3]=(short)f2b(a.w);
  r[4]=(short)f2b(b.x); r[5]=(short)f2b(b.y); r[6]=(short)f2b(b.z); r[7]=(short)f2b(b.w);
  return r;
}

// async global->LDS, 16B per lane; LDS dest = wave-uniform base + lane*16
static __device__ __forceinline__ void gld16(const void* g, void* l){
  __builtin_amdgcn_global_load_lds(
      (const __attribute__((address_space(1))) u32*)g,
      (__attribute__((address_space(3))) u32*)l, 16, 0, 0);
}

// bank swizzle selector for [row][slot] k-chunk layout: 2-way max on ds_read_b128
#define SW(x) ((((x)&3) ^ (((x)>>2)&3)))

// ---------------------------------------------------------------------------
// All fp32->bf16 conversions in ONE kernel (block-range dispatch).
// ranges (blocks of 2048 elems): att 12544 | aw-pad 256 | wi 3072 | wh 3072 |
//                                wa 3072 | pw 2372
// ---------------------------------------------------------------------------
static __device__ __forceinline__ void cvt_range(const float* __restrict__ s,
                                                 short* __restrict__ d,
                                                 int lb, int t, int n){
  const int i8 = (lb * 256 + t) * 8;
  if (i8 >= n) return;
  float4 a = *(const float4*)(s + i8);
  float4 b = *(const float4*)(s + i8 + 4);
  *(bf16x8*)(d + i8) = cvt8(a, b);
}

__global__ __launch_bounds__(256) void k_cvt_all(
    const float* __restrict__ att,  const float* __restrict__ a2aw,
    const float* __restrict__ i2hw, const float* __restrict__ h2hw,
    const float* __restrict__ a2hw, const float* __restrict__ pw,
    short* __restrict__ att_bf, short* __restrict__ awp,
    short* __restrict__ wi, short* __restrict__ wh,
    short* __restrict__ wa, short* __restrict__ pwb)
{
  const int bid = blockIdx.x, t = threadIdx.x;
  if (bid < 12544) {
    cvt_range(att, att_bf, bid, t, 25690112);
  } else if (bid < 12800) {
    // a2a_w [4][196][512] -> padded [4][256][512], rows 196..255 zero
    const int idx8 = ((bid - 12544) * 256 + t) * 8;   // < 524288
    const int g   = idx8 >> 17;
    const int rem = idx8 & 131071;
    const int row = rem >> 9;
    const int k   = rem & 511;
    bf16x8 v;
    if (row < A_) {
      const float* sp = a2aw + ((size_t)g * A_ + row) * R_ + k;
      v = cvt8(*(const float4*)sp, *(const float4*)(sp + 4));
    } else {
      v = (bf16x8){0,0,0,0,0,0,0,0};
    }
    *(bf16x8*)(awp + idx8) = v;
  } else if (bid < 15872) {
    cvt_range(i2hw, wi, bid - 12800, t, 6291456);
  } else if (bid < 18944) {
    cvt_range(h2hw, wh, bid - 15872, t, 6291456);
  } else if (bid < 22016) {
    cvt_range(a2hw, wa, bid - 18944, t, 6291456);
  } else {
    cvt_range(pw, pwb, bid - 22016, t, 4857344);
  }
}

// ---------------------------------------------------------------------------
// Score: double-buffered global_load_lds MFMA GEMM + fused hh GEMV + epilogue.
// C[m,n] = att_bf[m,:] @ wbf[n,:]^T  (M=64/block, Npad=256(224 staged), K=512)
// hh[m]  = h[b]·h2aw[a] + h2ab[a]  (computed in prologue, hidden under DMA)
// score[m] = sum_n tanh(C + bpad[n] + hh[m]) * wpad[n] + d2db
// ---------------------------------------------------------------------------
__global__ __launch_bounds__(256) void k_score_mfma(
    const short* __restrict__ att_bf, const short* __restrict__ wbf,
    const float* __restrict__ a2ab, const float* __restrict__ d2dw,
    const float* __restrict__ d2db,
    const float* __restrict__ h, const float* __restrict__ h2aw,
    const float* __restrict__ h2ab,
    float* __restrict__ score)
{
  __shared__ __align__(16) short As[2][256 * 8];    // 2 x 4 KiB
  __shared__ __align__(16) short Bs[2][1024 * 8];   // 2 x 16 KiB
  __shared__ float wpad[256], bpad[256], hhs[64], sred[2][64];
  __shared__ float hred[64][4];

  const int t   = threadIdx.x;
  const int m0  = blockIdx.x * 64;
  const int wid = t >> 6, l = t & 63;
  const int wr  = wid >> 1, wc = wid & 1;
  const int q   = l >> 4, lc = l & 15;

  // per-lane staging coords
  const int a_row  = t >> 2;                 // 0..63
  const int a_kb   = (t & 3) ^ SW(a_row);
  const short* a_g = att_bf + (size_t)(m0 + a_row) * R_ + a_kb * 8;
  int b_n[4], b_kb[4];
#pragma unroll
  for (int j = 0; j < 4; ++j) {
    b_n[j]  = j * 64 + (t >> 2);
    b_kb[j] = (t & 3) ^ SW(b_n[j]);
  }

#define STAGE(bufi, kz) {                                                 \
    gld16((const void*)(a_g + (kz)), (void*)&As[bufi][wid * 512]);        \
    _Pragma("unroll")                                                     \
    for (int j = 0; j < 4; ++j)                                           \
      gld16((const void*)(wbf + (size_t)b_n[j] * R_ + (kz) + b_kb[j] * 8),\
            (void*)&Bs[bufi][j * 2048 + wid * 512]);                      \
  }

  STAGE(0, 0);

  // ---- prologue work while first DMA is in flight ----
  wpad[t] = (t < A_) ? d2dw[t] : 0.f;
  bpad[t] = (t < A_) ? a2ab[t] : 0.f;
  {
    const int hr = t >> 2, hseg = t & 3;
    const int hm = m0 + hr;
    const int hb_ = hm / A_;
    const int ha_ = hm - hb_ * A_;
    const float* hp = h    + (size_t)hb_ * R_ + hseg * 128;
    const float* wp = h2aw + (size_t)ha_ * R_ + hseg * 128;
    float p = 0.f;
#pragma unroll
    for (int k = 0; k < 128; k += 4) {
      float4 a4 = *(const float4*)(hp + k);
      float4 b4 = *(const float4*)(wp + k);
      p = fmaf(a4.x, b4.x, p); p = fmaf(a4.y, b4.y, p);
      p = fmaf(a4.z, b4.z, p); p = fmaf(a4.w, b4.w, p);
    }
    hred[hr][hseg] = p;
  }

  f32x4 acc[2][8];
#pragma unroll
  for (int i = 0; i < 2; ++i)
#pragma unroll
    for (int j = 0; j < 8; ++j) acc[i][j] = (f32x4){0.f, 0.f, 0.f, 0.f};

  __syncthreads();   // hred complete + STAGE(0) drained

  if (t < 64) {
    const int m = m0 + t;
    const int b2 = m / A_;
    const int a2 = m - b2 * A_;
    hhs[t] = hred[t][0] + hred[t][1] + hred[t][2] + hred[t][3] + h2ab[a2];
  }

  for (int ks = 0; ks < 16; ++ks) {
    const int cur = ks & 1;
    if (ks < 15) STAGE(cur ^ 1, (ks + 1) * 32);
    bf16x8 af[2], bfr[8];
#pragma unroll
    for (int mf = 0; mf < 2; ++mf) {
      const int row = wr * 32 + mf * 16 + lc;
      af[mf] = *(const bf16x8*)&As[cur][(row * 4 + (q ^ SW(row))) * 8];
    }
#pragma unroll
    for (int nf = 0; nf < 8; ++nf) {
      const int n = wc * 128 + nf * 16 + lc;
      bfr[nf] = *(const bf16x8*)&Bs[cur][(n * 4 + (q ^ SW(n))) * 8];
    }
#pragma unroll
    for (int mf = 0; mf < 2; ++mf)
#pragma unroll
      for (int nf = 0; nf < 8; ++nf)
        acc[mf][nf] = __builtin_amdgcn_mfma_f32_16x16x32_bf16(af[mf], bfr[nf], acc[mf][nf], 0, 0, 0);
    __syncthreads();
  }
#undef STAGE

  // epilogue
  float s[2][4];
#pragma unroll
  for (int mf = 0; mf < 2; ++mf)
#pragma unroll
    for (int r = 0; r < 4; ++r) s[mf][r] = 0.f;

#pragma unroll
  for (int mf = 0; mf < 2; ++mf) {
    const int rbase = wr * 32 + mf * 16 + q * 4;
#pragma unroll
    for (int nf = 0; nf < 8; ++nf) {
      const int col = wc * 128 + nf * 16 + lc;
      const float bp = bpad[col], wp = wpad[col];
#pragma unroll
      for (int r = 0; r < 4; ++r)
        s[mf][r] += tanhf(acc[mf][nf][r] + bp + hhs[rbase + r]) * wp;
    }
  }
#pragma unroll
  for (int mask = 1; mask <= 8; mask <<= 1) {
#pragma unroll
    for (int mf = 0; mf < 2; ++mf)
#pragma unroll
      for (int r = 0; r < 4; ++r) s[mf][r] += __shfl_xor(s[mf][r], mask);
  }
  if (lc == 0) {
#pragma unroll
    for (int mf = 0; mf < 2; ++mf)
#pragma unroll
      for (int r = 0; r < 4; ++r)
        sred[wc][wr * 32 + mf * 16 + q * 4 + r] = s[mf][r];
  }
  __syncthreads();
  if (t < 64) score[m0 + t] = sred[0][t] + sred[1][t] + d2db[0];
}

// ---------------------------------------------------------------------------
// Fused softmax(196) + att_res (+ optional top_h/out/xt epilogue).
// grid (B_); 256 threads; thread t handles r = 2t, 2t+1.
// fuse=0: attres[b,r] = sum_a att[b,a,r] * w[b,a]
// fuse=1: v = attres + nh; out_slot=v; toph=v; xt = x + v
// ---------------------------------------------------------------------------
__global__ __launch_bounds__(256) void k_smax_attres(
    const float* __restrict__ sc, const short* __restrict__ att_bf,
    const float* __restrict__ nh, const float* __restrict__ x,
    float* __restrict__ attres, float* __restrict__ out_slot,
    float* __restrict__ toph, float* __restrict__ xt, int fuse)
{
  __shared__ float red[256];
  __shared__ float wl[256];
  const int b = blockIdx.x, t = threadIdx.x;
  const float v = (t < A_) ? sc[b * A_ + t] : -INFINITY;
  red[t] = v; __syncthreads();
  for (int s = 128; s > 0; s >>= 1) { if (t < s) red[t] = fmaxf(red[t], red[t+s]); __syncthreads(); }
  const float mx = red[0]; __syncthreads();
  const float e = (t < A_) ? expf(v - mx) : 0.f;
  red[t] = e; __syncthreads();
  for (int s = 128; s > 0; s >>= 1) { if (t < s) red[t] += red[t+s]; __syncthreads(); }
  wl[t] = e / red[0];
  __syncthreads();

  const int r0 = t * 2;
  const u32* ap = (const u32*)(att_bf + (size_t)b * A_ * R_ + r0);
  float acc0 = 0.f, acc1 = 0.f;
#pragma unroll 4
  for (int a = 0; a < A_; ++a) {
    const u32 pk = ap[(size_t)a * 256];   // 512 shorts = 256 u32
    const float w = wl[a];
    acc0 = fmaf(b2f((unsigned short)(pk & 0xffffu)), w, acc0);
    acc1 = fmaf(b2f((unsigned short)(pk >> 16)),     w, acc1);
  }
  const int idx0 = b * R_ + r0;
  if (!fuse) {
    attres[idx0]     = acc0;
    attres[idx0 + 1] = acc1;
  } else {
    const float v0 = acc0 + nh[idx0];
    const float v1 = acc1 + nh[idx0 + 1];
    out_slot[idx0]     = v0;  out_slot[idx0 + 1] = v1;
    toph[idx0]         = v0;  toph[idx0 + 1]     = v1;
    xt[idx0]           = x[idx0] + v0;
    xt[idx0 + 1]       = x[idx0 + 1] + v1;
  }
}

// ---------------------------------------------------------------------------
// LSTM gate GEMMs: 3 independent GEMMs (xt·wi, ph·wh, ar·wa) via blockIdx.z.
// Each: M=64 tile (b), N=128 tile, K=512 (16 steps). Partial -> psums[z].
// ---------------------------------------------------------------------------
__global__ __launch_bounds__(256) void k_lstm_mfma(
    const float* __restrict__ xt, const float* __restrict__ ph, const float* __restrict__ ar,
    const short* __restrict__ wi, const short* __restrict__ wh, const short* __restrict__ wa,
    int layer, float* __restrict__ psums)
{
  __shared__ __align__(16) short As[4 * 64 * 8];
  __shared__ __align__(16) short Bs[4 * 128 * 8];

  const int t   = threadIdx.x;
  const int m0  = blockIdx.x * 64;
  const int n0  = blockIdx.y * 128;
  const int z   = blockIdx.z;
  const int wid = t >> 6, l = t & 63;
  const int wr  = wid >> 1, wc = wid & 1;
  const int q   = l >> 4, lc = l & 15;

  const float* asel = (z == 0) ? xt : (z == 1) ? ph : ar;
  const short* wsel = (z == 0) ? wi : (z == 1) ? wh : wa;
  const size_t wrow0 = ((size_t)layer * 6144 + n0) * R_;

  f32x4 acc[2][4];
#pragma unroll
  for (int i = 0; i < 2; ++i)
#pragma unroll
    for (int j = 0; j < 4; ++j) acc[i][j] = (f32x4){0.f, 0.f, 0.f, 0.f};

  const int s_row = t >> 2, s_kb = t & 3;

  float4 ra0, ra1;
  bf16x8 rb0, rb1;

#define LS_LOAD(ks) {                                                   \
    const int kk = (ks) * 32;                                           \
    const float* ap = asel + (size_t)(m0 + s_row) * R_ + kk + s_kb * 8; \
    ra0 = *(const float4*)ap;                                           \
    ra1 = *(const float4*)(ap + 4);                                     \
    const short* bp0 = wsel + wrow0 + (size_t)(s_row      ) * R_ + kk + s_kb * 8; \
    const short* bp1 = wsel + wrow0 + (size_t)(s_row +  64) * R_ + kk + s_kb * 8; \
    rb0 = *(const bf16x8*)bp0;                                          \
    rb1 = *(const bf16x8*)bp1;                                          \
  }
#define LS_STORE() {                                                    \
    *(bf16x8*)&As[s_kb * 512  + s_row * 8] = cvt8(ra0, ra1);            \
    *(bf16x8*)&Bs[s_kb * 1024 + (s_row      ) * 8] = rb0;               \
    *(bf16x8*)&Bs[s_kb * 1024 + (s_row + 64) * 8] = rb1;                \
  }

  LS_LOAD(0);
  for (int ks = 0; ks < 16; ++ks) {
    __syncthreads();
    LS_STORE();
    __syncthreads();
    if (ks < 15) LS_LOAD(ks + 1);
    bf16x8 af[2], bfr[4];
#pragma unroll
    for (int mf = 0; mf < 2; ++mf) {
      const int row = wr * 32 + mf * 16 + lc;
      af[mf] = *(const bf16x8*)&As[q * 512 + row * 8];
    }
#pragma unroll
    for (int nf = 0; nf < 4; ++nf) {
      const int n = wc * 64 + nf * 16 + lc;
      bfr[nf] = *(const bf16x8*)&Bs[q * 1024 + n * 8];
    }
#pragma unroll
    for (int mf = 0; mf < 2; ++mf)
#pragma unroll
      for (int nf = 0; nf < 4; ++nf)
        acc[mf][nf] = __builtin_amdgcn_mfma_f32_16x16x32_bf16(af[mf], bfr[nf], acc[mf][nf], 0, 0, 0);
  }
#undef LS_LOAD
#undef LS_STORE

  float* zout = psums + (size_t)z * SSZ;
#pragma unroll
  for (int mf = 0; mf < 2; ++mf) {
#pragma unroll
    for (int nf = 0; nf < 4; ++nf) {
      const int col = n0 + wc * 64 + nf * 16 + lc;
      const int p = col >> 11, g = col & 2047;
#pragma unroll
      for (int r = 0; r < 4; ++r) {
        const int b = m0 + wr * 32 + mf * 16 + q * 4 + r;
        zout[((size_t)p * B_ + b) * (size_t)G4 + g] = acc[mf][nf][r];
      }
    }
  }
}

__global__ __launch_bounds__(256) void k_lstm_elem(
    const float* __restrict__ psums,
    const float* __restrict__ i2hb, const float* __restrict__ h2hb, const float* __restrict__ a2hb,
    const float* __restrict__ prev_c, int layer,
    float* __restrict__ out_c, float* __restrict__ next_h)
{
  const int idx = blockIdx.x * 256 + threadIdx.x;
  const int b = idx >> 9, r = idx & 511;
  const size_t boff = (size_t)layer * P_ * G4;
  const float pc = prev_c[idx];
  float aC = 0.f, aH = 0.f;
#pragma unroll
  for (int p = 0; p < P_; ++p) {
    const size_t base = ((size_t)p * B_ + b) * (size_t)G4;
    const float* s0 = psums + base;
    const float* s1 = psums + SSZ + base;
    const float* s2 = psums + 2 * (size_t)SSZ + base;
    const float* b1 = i2hb + boff + p * G4;
    const float* b2 = h2hb + boff + p * G4;
    const float* b3 = a2hb + boff + p * G4;
    const float gi = s0[r]      + s1[r]      + s2[r]      + b1[r]      + b2[r]      + b3[r];
    const float gf = s0[r+512]  + s1[r+512]  + s2[r+512]  + b1[r+512]  + b2[r+512]  + b3[r+512];
    const float go = s0[r+1024] + s1[r+1024] + s2[r+1024] + b1[r+1024] + b2[r+1024] + b3[r+1024];
    const float gt = s0[r+1536] + s1[r+1536] + s2[r+1536] + b1[r+1536] + b2[r+1536] + b3[r+1536];
    const float ig = 1.f / (1.f + expf(-gi));
    const float fg = 1.f / (1.f + expf(-gf));
    const float og = 1.f / (1.f + expf(-go));
    const float it = tanhf(gt);
    const float nc = fg * pc + ig * it;
    const float nh = og * tanhf(nc);
    aC += nc; aH += nh;
  }
  out_c[idx]  = aC * (1.f/3.f);
  next_h[idx] = aH * (1.f/3.f);
}

// ---------------------------------------------------------------------------
// Projection GEMM via MFMA (unchanged).
// ---------------------------------------------------------------------------
__global__ __launch_bounds__(256) void k_proj_mfma(
    const float* __restrict__ th, const short* __restrict__ pwb,
    const float* __restrict__ pb, float* __restrict__ logits)
{
  __shared__ __align__(16) short As[4 * 64 * 8];
  __shared__ __align__(16) short Bs[4 * 128 * 8];

  const int t   = threadIdx.x;
  const int m0  = blockIdx.x * 64;
  const int n0  = blockIdx.y * 128;
  const int wid = t >> 6, l = t & 63;
  const int wr  = wid >> 1, wc = wid & 1;
  const int q   = l >> 4, lc = l & 15;

  f32x4 acc[2][4];
#pragma unroll
  for (int i = 0; i < 2; ++i)
#pragma unroll
    for (int j = 0; j < 4; ++j) acc[i][j] = (f32x4){0.f, 0.f, 0.f, 0.f};

  const int s_row = t >> 2, s_kb = t & 3;
  const int ng0 = n0 + s_row, ng1 = n0 + s_row + 64;

  float4 ra0, ra1;
  bf16x8 rb0, rb1;

#define PJ_LOAD(ks) {                                                   \
    const int kk = (ks) * 32;                                           \
    const float* ap = th + (size_t)(m0 + s_row) * R_ + kk + s_kb * 8;   \
    ra0 = *(const float4*)ap;                                           \
    ra1 = *(const float4*)(ap + 4);                                     \
    if (ng0 < V_) rb0 = *(const bf16x8*)(pwb + (size_t)ng0 * R_ + kk + s_kb * 8); \
    else          rb0 = (bf16x8){0,0,0,0,0,0,0,0};                      \
    if (ng1 < V_) rb1 = *(const bf16x8*)(pwb + (size_t)ng1 * R_ + kk + s_kb * 8); \
    else          rb1 = (bf16x8){0,0,0,0,0,0,0,0};                      \
  }
#define PJ_STORE() {                                                    \
    *(bf16x8*)&As[s_kb * 512  + s_row * 8] = cvt8(ra0, ra1);            \
    *(bf16x8*)&Bs[s_kb * 1024 + (s_row      ) * 8] = rb0;               \
    *(bf16x8*)&Bs[s_kb * 1024 + (s_row + 64) * 8] = rb1;                \
  }

  PJ_LOAD(0);
  for (int ks = 0; ks < 16; ++ks) {
    __syncthreads();
    PJ_STORE();
    __syncthreads();
    if (ks < 15) PJ_LOAD(ks + 1);
    bf16x8 af[2], bfr[4];
#pragma unroll
    for (int mf = 0; mf < 2; ++mf) {
      const int row = wr * 32 + mf * 16 + lc;
      af[mf] = *(const bf16x8*)&As[q * 512 + row * 8];
    }
#pragma unroll
    for (int nf = 0; nf < 4; ++nf) {
      const int n = wc * 64 + nf * 16 + lc;
      bfr[nf] = *(const bf16x8*)&Bs[q * 1024 + n * 8];
    }
#pragma unroll
    for (int mf = 0; mf < 2; ++mf)
#pragma unroll
      for (int nf = 0; nf < 4; ++nf)
        acc[mf][nf] = __builtin_amdgcn_mfma_f32_16x16x32_bf16(af[mf], bfr[nf], acc[mf][nf], 0, 0, 0);
  }
#undef PJ_LOAD
#undef PJ_STORE

#pragma unroll
  for (int mf = 0; mf < 2; ++mf) {
#pragma unroll
    for (int nf = 0; nf < 4; ++nf) {
      const int col = n0 + wc * 64 + nf * 16 + lc;
      if (col < V_) {
        const float bias = pb[col];
#pragma unroll
        for (int r = 0; r < 4; ++r) {
          const int b = m0 + wr * 32 + mf * 16 + q * 4 + r;
          logits[(size_t)b * V_ + col] = acc[mf][nf][r] + bias;
        }
      }
    }
  }
}

__global__ __launch_bounds__(256) void k_logsoftmax(
    const float* __restrict__ logits, float* __restrict__ out)
{
  __shared__ float red[256];
  const int b = blockIdx.x, t = threadIdx.x;
  const float* lp = logits + (size_t)b * V_;
  float mx = -INFINITY;
  for (int n = t; n < V_; n += 256) mx = fmaxf(mx, lp[n]);
  red[t] = mx; __syncthreads();
  for (int s = 128; s > 0; s >>= 1) { if (t < s) red[t] = fmaxf(red[t], red[t+s]); __syncthreads(); }
  mx = red[0]; __syncthreads();
  float sm = 0.f;
  for (int n = t; n < V_; n += 256) sm += expf(lp[n] - mx);
  red[t] = sm; __syncthreads();
  for (int s = 128; s > 0; s >>= 1) { if (t < s) red[t] += red[t+s]; __syncthreads(); }
  const float lse = mx + logf(red[0]);
  float* op = out + (size_t)b * V_;
  for (int n = t; n < V_; n += 256) op[n] = lp[n] - lse;
}

extern "C" void kernel_launch(void* const* d_in, const int* in_sizes, int n_in,
                              void* d_out, int out_size, void* d_ws, size_t ws_size,
                              hipStream_t stream)
{
  const float* x      = (const float*)d_in[0];
  const float* att    = (const float*)d_in[1];
  const float* inputs = (const float*)d_in[2];
  const float* i2hw   = (const float*)d_in[3];
  const float* i2hb   = (const float*)d_in[4];
  const float* h2hw   = (const float*)d_in[5];
  const float* h2hb   = (const float*)d_in[6];
  const float* a2hw   = (const float*)d_in[7];
  const float* a2hb   = (const float*)d_in[8];
  const float* a2aw   = (const float*)d_in[9];
  const float* a2ab   = (const float*)d_in[10];
  const float* h2aw   = (const float*)d_in[11];
  const float* h2ab   = (const float*)d_in[12];
  const float* d2dw   = (const float*)d_in[13];
  const float* d2db   = (const float*)d_in[14];
  const float* pw     = (const float*)d_in[15];
  const float* pb     = (const float*)d_in[16];
  float* out = (float*)d_out;
  float* ws  = (float*)d_ws;

  // fp32 scratch (float offsets)
  float* w_score  = ws + 0;        //   51200 (pad)
  float* w_attres = ws + 51200;    //  131072
  float* w_xt     = ws + 182272;   //  131072
  float* w_nexth  = ws + 313344;   //  131072
  float* w_toph   = ws + 444416;   //  131072
  float* w_sums3  = ws + 575488;   // 3*1572864 = 4718592
  float* w_logits = ws + 5294080;  // 2428672 -> ends 7722752

  // bf16 region (byte offset 30891008, 16B aligned)
  short* bfbase = (short*)(ws + 7722752);
  short* att_bf = bfbase;                       // 25,690,112
  short* awp_bf = bfbase + 25690112;            //    524,288 (padded 4x256x512)
  short* wi_bf  = bfbase + 26214400;            //  6,291,456
  short* wh_bf  = bfbase + 32505856;            //  6,291,456
  short* wa_bf  = bfbase + 38797312;            //  6,291,456
  short* pw_bf  = bfbase + 45088768;            //  4,857,344
  // end: 49,946,112 shorts; total ws ~131 MB

  // ---- all conversions, one kernel ----
  k_cvt_all<<<24388, 256, 0, stream>>>(att, a2aw, i2hw, h2hw, a2hw, pw,
                                       att_bf, awp_bf, wi_bf, wh_bf, wa_bf, pw_bf);

  const float* cur_x = x;
  for (int i = 0; i < L_; ++i) {
    const float* prev_c = inputs + (size_t)(2*i)   * BR;
    const float* prev_h = inputs + (size_t)(2*i+1) * BR;

    // --- att_res0 = soft_att(att, prev_h, weights[i,0]) ---
    {
      const int idx = i*2 + 0;
      k_score_mfma<<<784, 256, 0, stream>>>(att_bf, awp_bf + (size_t)idx*256*R_,
          a2ab + (size_t)idx*A_, d2dw + (size_t)idx*A_, d2db + idx,
          prev_h, h2aw + (size_t)idx*A_*R_, h2ab + (size_t)idx*A_, w_score);
      k_smax_attres<<<B_, 256, 0, stream>>>(w_score, att_bf,
          nullptr, nullptr, w_attres, nullptr, nullptr, nullptr, 0);
    }

    // --- LSTM: 3 independent GEMMs in parallel (blockIdx.z) ---
    k_lstm_mfma<<<dim3(4, 48, 3), 256, 0, stream>>>(cur_x, prev_h, w_attres,
                                                    wi_bf, wh_bf, wa_bf, i, w_sums3);
    k_lstm_elem<<<512, 256, 0, stream>>>(w_sums3, i2hb, h2hb, a2hb, prev_c, i,
                                         out + (size_t)(2*i) * BR, w_nexth);

    // --- att_res1 + fused top_h/out/xt ---
    {
      const int idx = i*2 + 1;
      k_score_mfma<<<784, 256, 0, stream>>>(att_bf, awp_bf + (size_t)idx*256*R_,
          a2ab + (size_t)idx*A_, d2dw + (size_t)idx*A_, d2db + idx,
          w_nexth, h2aw + (size_t)idx*A_*R_, h2ab + (size_t)idx*A_, w_score);
      k_smax_attres<<<B_, 256, 0, stream>>>(w_score, att_bf,
          w_nexth, x, nullptr, out + (size_t)(2*i+1) * BR, w_toph, w_xt, 1);
    }
    cur_x = w_xt;
  }

  k_proj_mfma<<<dim3(4, 75), 256, 0, stream>>>(w_toph, pw_bf, pb, w_logits);
  k_logsoftmax<<<B_, 256, 0, stream>>>(w_logits, out + (size_t)4 * BR);
}